// Round 12
// baseline (418.783 us; speedup 1.0000x reference)
//
#include <hip/hip_runtime.h>

#define NN 50000
#define NE 400000
#define NG 32
#define SLOPE 0.2f
#define NSB ((NN + 255) / 256)   // 196 scan blocks

typedef __attribute__((ext_vector_type(4))) float f32x4;
typedef __attribute__((ext_vector_type(16))) float f32x16;
typedef __attribute__((ext_vector_type(8))) short s16x8;

__device__ __forceinline__ float lrelu(float v) { return v > 0.f ? v : SLOPE * v; }
__device__ __forceinline__ unsigned short f2bf(float f) {
    union { float f; unsigned u; } c; c.f = f;
    unsigned r = c.u + 0x7fffu + ((c.u >> 16) & 1u);
    return (unsigned short)(r >> 16);
}
__device__ __forceinline__ float bf2f(unsigned short b) {
    union { unsigned u; float f; } c; c.u = ((unsigned)b) << 16; return c.f;
}
__device__ __forceinline__ unsigned pack2(float a, float b) {
    return (unsigned)f2bf(a) | ((unsigned)f2bf(b) << 16);
}
__device__ __forceinline__ uint2 pack_bf4(float a, float b, float c, float d) {
    uint2 u;
    u.x = pack2(a, b);
    u.y = pack2(c, d);
    return u;
}

// ---------------- CSR build ----------------
__global__ __launch_bounds__(256) void k_hist(const int* __restrict__ dst, int* __restrict__ deg) {
    int e = blockIdx.x * 256 + threadIdx.x;
    if (e < NE) atomicAdd(&deg[dst[e]], 1);
}

__global__ __launch_bounds__(256) void k_bsum(const int* __restrict__ deg, int* __restrict__ bsum) {
    __shared__ int ls[256];
    const int t = threadIdx.x;
    const int idx = blockIdx.x * 256 + t;
    ls[t] = (idx < NN) ? deg[idx] : 0;
    __syncthreads();
#pragma unroll
    for (int off = 128; off; off >>= 1) {
        if (t < off) ls[t] += ls[t + off];
        __syncthreads();
    }
    if (t == 0) bsum[blockIdx.x] = ls[0];
}

__global__ __launch_bounds__(256) void k_scan2(const int* __restrict__ deg,
                                               const int* __restrict__ bsum,
                                               int* __restrict__ rowptr, int* __restrict__ cursor) {
    __shared__ int lb[256];
    __shared__ int ls[256];
    const int t = threadIdx.x, b = blockIdx.x;
    lb[t] = (t < NSB && t < b) ? bsum[t] : 0;
    const int idx = b * 256 + t;
    const int v = (idx < NN) ? deg[idx] : 0;
    ls[t] = v;
    __syncthreads();
#pragma unroll
    for (int off = 128; off; off >>= 1) {
        if (t < off) lb[t] += lb[t + off];
        __syncthreads();
    }
#pragma unroll
    for (int off = 1; off < 256; off <<= 1) {
        int u = (t >= off) ? ls[t - off] : 0;
        __syncthreads();
        ls[t] += u;
        __syncthreads();
    }
    if (idx < NN) {
        const int run = lb[0] + ls[t] - v;
        rowptr[idx] = run;
        cursor[idx] = run;
    }
    if (b == 0 && t == 0) rowptr[NN] = NE;
}

__global__ __launch_bounds__(256) void k_perm(const int* __restrict__ dst, const int* __restrict__ src,
                                              int* __restrict__ cursor, int* __restrict__ eid,
                                              int* __restrict__ srcp) {
    int e = blockIdx.x * 256 + threadIdx.x;
    if (e < NE) {
        int p = atomicAdd(&cursor[dst[e]], 1);
        eid[p] = e;
        srcp[p] = src[e];
    }
}

// ---------------- one-time weight prep ----------------
__global__ __launch_bounds__(256) void k_wprep(const float* __restrict__ w3,
                                               const float* __restrict__ w2,
                                               const float* __restrict__ w1,
                                               const float* __restrict__ b1,
                                               const float* __restrict__ b3,
                                               unsigned short* __restrict__ w3t_g,
                                               unsigned short* __restrict__ w2t_g,
                                               unsigned short* __restrict__ w1p_g,
                                               unsigned short* __restrict__ b3t_g) {
    const int v = blockIdx.x * 256 + threadIdx.x;
    if (v < 64 * 512) {
        const int k = v >> 9, n = v & 511;
        const int byte = (n << 7) | ((k << 1) ^ ((n & 7) << 4));
        *(unsigned short*)((char*)w3t_g + byte) = f2bf(w3[v]);
    }
    if (v < 64 * 128) {
        const int o = v & 63, slot = v >> 6;
        const int ks = slot >> 4, lg2 = (slot >> 3) & 1, j = slot & 7;
        const int kp = (ks >> 1) * 32 + (j & 3) + 8 * (j >> 2) + 16 * (ks & 1) + 4 * lg2;
        const int byte = (o << 8) | ((slot << 1) ^ ((o & 7) << 4));
        *(unsigned short*)((char*)w2t_g + byte) = f2bf(w2[kp * 64 + o]);
    }
    if (v < 128 * 16) {
        const int j = v >> 4, k = v & 15;
        float val = (k < 3) ? w1[k * 128 + j] : (k == 3 ? b1[j] : 0.f);
        w1p_g[v] = f2bf(val);
    }
    if (v < 512) {
        const int i = v >> 5, o = v & 31;
        b3t_g[o * 16 + i] = f2bf(b3[v]);
    }
}

// ---------------- fused NNConv, all-MFMA, 32 edges/chunk, 16 waves/block ----------------
#define FUSED_GRID 256
#define NCHUNK (NE / 32)
__global__ __launch_bounds__(1024) void k_fused(
    const float* __restrict__ ea,
    const unsigned short* __restrict__ w1p_g,
    const unsigned short* __restrict__ w2t_g, const float* __restrict__ b2,
    const unsigned short* __restrict__ w3t_g, const unsigned short* __restrict__ b3t_g,
    const int* __restrict__ src, const float* __restrict__ x,
    unsigned short* __restrict__ msg)
{
    __shared__ __align__(16) unsigned short w3t[512 * 64];  // 64 KB
    __shared__ __align__(16) unsigned short w2t[64 * 128];  // 16 KB
    __shared__ __align__(16) unsigned short w1p[128 * 16];  // 4 KB
    __shared__ __align__(16) unsigned short b3t[512];       // 1 KB
    __shared__ __align__(16) float b2s[64];
    __shared__ __align__(16) unsigned slab[16][1024];       // 64 KB (4 KB/wave)

    const int t = threadIdx.x;
    {
        const uint4* g = (const uint4*)w3t_g;
        uint4* l = (uint4*)w3t;
        for (int v = t; v < 4096; v += 1024) l[v] = g[v];
        const uint4* g2 = (const uint4*)w2t_g;
        uint4* l2 = (uint4*)w2t;
        if (t < 1024) { if (t < 1024) l2[t % 1024] = g2[t % 1024]; }
    }
    if (t < 256) ((uint4*)w1p)[t] = ((const uint4*)w1p_g)[t];
    if (t < 64)  ((uint4*)b3t)[t] = ((const uint4*)b3t_g)[t];
    if (t < 64)  b2s[t] = b2[t];
    __syncthreads();

    const int wid = t >> 6, lane = t & 63;
    const int l31 = lane & 31, lg2 = lane >> 5;
    char* sw = (char*)slab[wid];
    const int swz = (l31 & 7) << 4;

    s16x8 w1pf[4];
#pragma unroll
    for (int n = 0; n < 4; ++n)
        w1pf[n] = *(const s16x8*)((const char*)w1p + ((n * 32 + l31) << 5) + lg2 * 16);
    s16x8 b3f = *(const s16x8*)((const char*)b3t + (l31 << 5) + lg2 * 16);

    for (int chunk = blockIdx.x * 16 + wid; chunk < NCHUNK; chunk += FUSED_GRID * 16) {
        const int e = chunk * 32 + l31;
        const int sn = src[e];
        const f32x4* __restrict__ xp = (const f32x4*)(x + (size_t)sn * 16);
        f32x4 x0 = xp[0], x1 = xp[1], x2 = xp[2], x3 = xp[3];
        const float ea0 = ea[e * 3], ea1 = ea[e * 3 + 1], ea2 = ea[e * 3 + 2];

        // ---- L1: 4 MFMAs, pack D into L2 B-fragments ----
        s16x8 eb = (s16x8){0, 0, 0, 0, 0, 0, 0, 0};
        if (lg2 == 0) {
            eb[0] = (short)f2bf(ea0); eb[1] = (short)f2bf(ea1);
            eb[2] = (short)f2bf(ea2); eb[3] = (short)0x3F80;  // 1.0
        }
        s16x8 hb[8];
#pragma unroll
        for (int n = 0; n < 4; ++n) {
            f32x16 d = {0.f};
            d = __builtin_amdgcn_mfma_f32_32x32x16_bf16(w1pf[n], eb, d, 0, 0, 0);
#pragma unroll
            for (int s = 0; s < 2; ++s)
#pragma unroll
                for (int j = 0; j < 8; ++j)
                    hb[2 * n + s][j] = (short)f2bf(fmaxf(d[(j & 3) + 4 * (j >> 2) + 8 * s], 0.f));
        }

        // ---- L2: h2 = relu(w2t @ h1 + b2), 16 MFMAs; b2 added at pack from LDS ----
        asm volatile("s_waitcnt lgkmcnt(0)" ::: "memory");
#pragma unroll
        for (int nblk = 0; nblk < 2; ++nblk) {
            f32x16 a2 = {0.f};
            const char* __restrict__ w2row = (const char*)w2t + ((nblk * 32 + l31) << 8);
#pragma unroll
            for (int ks = 0; ks < 8; ++ks) {
                s16x8 a = *(const s16x8*)(w2row + ((ks * 32 + lg2 * 16) ^ swz));
                a2 = __builtin_amdgcn_mfma_f32_32x32x16_bf16(a, hb[ks], a2, 0, 0, 0);
            }
#pragma unroll
            for (int rh = 0; rh < 4; ++rh) {
                const f32x4 bv = *(const f32x4*)(b2s + nblk * 32 + rh * 8 + lg2 * 4);
                const int kb = nblk * 64 + rh * 16 + lg2 * 8;
                *(uint2*)(sw + l31 * 128 + (kb ^ swz)) =
                    pack_bf4(fmaxf(a2[rh * 4] + bv[0], 0.f), fmaxf(a2[rh * 4 + 1] + bv[1], 0.f),
                             fmaxf(a2[rh * 4 + 2] + bv[2], 0.f), fmaxf(a2[rh * 4 + 3] + bv[3], 0.f));
            }
        }
        asm volatile("s_waitcnt lgkmcnt(0)" ::: "memory");

        s16x8 wb[4];
#pragma unroll
        for (int ks = 0; ks < 4; ++ks)
            wb[ks] = *(const s16x8*)(sw + l31 * 128 + ((ks * 32 + lg2 * 16) ^ swz));

        s16x8 xbf;
        {
            f32x4 a0 = lg2 ? x2 : x0, a1 = lg2 ? x3 : x1;
#pragma unroll
            for (int i = 0; i < 4; ++i) {
                xbf[i] = (short)f2bf(a0[i]);
                xbf[i + 4] = (short)f2bf(a1[i]);
            }
        }
        f32x16 p = {0.f};
        p = __builtin_amdgcn_mfma_f32_32x32x16_bf16(b3f, xbf, p, 0, 0, 0);

#pragma unroll
        for (int nblk = 0; nblk < 16; ++nblk) {
            const char* __restrict__ arow = (const char*)w3t + ((nblk * 32 + l31) << 7);
            f32x16 d = {0.f};
#pragma unroll
            for (int ks = 0; ks < 4; ++ks) {
                s16x8 a = *(const s16x8*)(arow + ((ks * 32 + lg2 * 16) ^ swz));
                d = __builtin_amdgcn_mfma_f32_32x32x16_bf16(a, wb[ks], d, 0, 0, 0);
            }
            const float xs = (nblk < 4 ? x0 : nblk < 8 ? x1 : nblk < 12 ? x2 : x3)[nblk & 3];
#pragma unroll
            for (int r = 0; r < 16; ++r) p[r] = fmaf(xs, d[r], p[r]);
        }

        asm volatile("s_waitcnt lgkmcnt(0)" ::: "memory");
#pragma unroll
        for (int rh = 0; rh < 4; ++rh) {
            const int ob = rh * 16 + lg2 * 8;
            *(uint2*)(sw + l31 * 64 + (ob ^ ((l31 & 7) << 3))) =
                pack_bf4(p[rh * 4], p[rh * 4 + 1], p[rh * 4 + 2], p[rh * 4 + 3]);
        }
        asm volatile("s_waitcnt lgkmcnt(0)" ::: "memory");
#pragma unroll
        for (int q = 0; q < 2; ++q) {
            const int er = (lane >> 2) + q * 16;
            const int off = (lane & 3) * 16;
            const int s8 = (er & 7) << 3;
            uint2 a = *(const uint2*)(sw + er * 64 + (off ^ s8));
            uint2 b = *(const uint2*)(sw + er * 64 + ((off + 8) ^ s8));
            *(uint4*)((char*)msg + (size_t)chunk * 2048 + q * 1024 + lane * 16) =
                make_uint4(a.x, a.y, b.x, b.y);
        }
    }
}

// ---------------- fused: agg (CSR gather) + root + GAT1 node transform ----------------
// One wave per node. h1 never touches memory: computed 32-wide, transformed to 64-wide
// via shfl broadcasts, as/ad reduced in-wave, hT written bf16-packed.
__global__ __launch_bounds__(256) void k_aggt(
    const unsigned short* __restrict__ msg, const int* __restrict__ rowptr,
    const int* __restrict__ eid, const float* __restrict__ x,
    const float* __restrict__ rw, const float* __restrict__ cb,
    const float* __restrict__ W, const float* __restrict__ av_s, const float* __restrict__ av_d,
    unsigned* __restrict__ hbf, float* __restrict__ as_v, float* __restrict__ ad_v)
{
    const int n = (blockIdx.x * 256 + threadIdx.x) >> 6;
    if (n >= NN) return;
    const int lane = threadIdx.x & 63;
    const int half = lane >> 5, o = lane & 31;
    const int r0 = rowptr[n], r1 = rowptr[n + 1];
    float agg = 0.f;
    for (int j = r0 + half; j < r1; j += 2)
        agg += bf2f(msg[(size_t)eid[j] * 32 + o]);
    agg += __shfl_xor(agg, 32);
    const float* __restrict__ xr = x + (size_t)n * 16;
    float root = cb[o];
#pragma unroll
    for (int i = 0; i < 16; ++i) root = fmaf(xr[i], rw[i * 32 + o], root);
    const float h1v = fmaxf(agg + root, 0.f);
    // transform 32 -> 64 (shfl broadcast; W is L1-hot 8KB)
    float acc = 0.f;
#pragma unroll 8
    for (int i = 0; i < 32; ++i)
        acc = fmaf(__shfl(h1v, i), W[i * 64 + lane], acc);
    float s = acc * av_s[lane], d = acc * av_d[lane];
#pragma unroll
    for (int off = 32; off; off >>= 1) { s += __shfl_xor(s, off); d += __shfl_xor(d, off); }
    if (lane == 0) { as_v[n] = s; ad_v[n] = d; }
    const float nb = __shfl(acc, lane | 1);
    if (!(lane & 1)) hbf[(size_t)n * 32 + (lane >> 1)] = pack2(acc, nb);
}

// asp[j] = as_v[srcp[j]]
__global__ __launch_bounds__(256) void k_easrc(const int* __restrict__ srcp,
                                               const float* __restrict__ as_v,
                                               float* __restrict__ asp) {
    int j = blockIdx.x * 256 + threadIdx.x;
    if (j < NE) asp[j] = as_v[srcp[j]];
}

// ---------------- GAT1: softmax-gather + fused layer-2 node transform ----------------
__global__ __launch_bounds__(256) void k_gat1(
    const int* __restrict__ rowptr, const int* __restrict__ srcp, const float* __restrict__ asp,
    const unsigned* __restrict__ hbf, const float* __restrict__ as_v, const float* __restrict__ ad_v,
    const float* __restrict__ b,
    const float* __restrict__ W2, const float* __restrict__ av_s2, const float* __restrict__ av_d2,
    unsigned* __restrict__ hbf2, float* __restrict__ as_v2, float* __restrict__ ad_v2)
{
    const int n = (blockIdx.x * 256 + threadIdx.x) >> 6;
    if (n >= NN) return;
    const int lane = threadIdx.x & 63;
    const int fl = lane & 15, qw = lane >> 4;
    const int r0 = rowptr[n], r1 = rowptr[n + 1];
    const float adn = ad_v[n];
    const float l_self = lrelu(as_v[n] + adn);
    float m = l_self;
    for (int j = r0 + lane; j < r1; j += 64)
        m = fmaxf(m, lrelu(asp[j] + adn));
#pragma unroll
    for (int off = 32; off; off >>= 1) m = fmaxf(m, __shfl_xor(m, off));
    float s = 0.f;
    for (int j = r0 + lane; j < r1; j += 64)
        s += expf(lrelu(asp[j] + adn) - m);
#pragma unroll
    for (int off = 32; off; off >>= 1) s += __shfl_xor(s, off);
    const float w_self = expf(l_self - m);
    s += w_self;
    float a0 = 0.f, a1 = 0.f, a2 = 0.f, a3 = 0.f;
    if (qw == 0) {
        const uint2 hv = *(const uint2*)(hbf + (size_t)n * 32 + fl * 2);
        a0 = w_self * bf2f((unsigned short)(hv.x & 0xffff));
        a1 = w_self * bf2f((unsigned short)(hv.x >> 16));
        a2 = w_self * bf2f((unsigned short)(hv.y & 0xffff));
        a3 = w_self * bf2f((unsigned short)(hv.y >> 16));
    }
    for (int j = r0 + qw; j < r1; j += 4) {
        const int sn = srcp[j];
        const float w = expf(lrelu(asp[j] + adn) - m);
        const uint2 hv = *(const uint2*)(hbf + (size_t)sn * 32 + fl * 2);
        a0 = fmaf(w, bf2f((unsigned short)(hv.x & 0xffff)), a0);
        a1 = fmaf(w, bf2f((unsigned short)(hv.x >> 16)), a1);
        a2 = fmaf(w, bf2f((unsigned short)(hv.y & 0xffff)), a2);
        a3 = fmaf(w, bf2f((unsigned short)(hv.y >> 16)), a3);
    }
#pragma unroll
    for (int off = 16; off <= 32; off <<= 1) {
        a0 += __shfl_xor(a0, off);
        a1 += __shfl_xor(a1, off);
        a2 += __shfl_xor(a2, off);
        a3 += __shfl_xor(a3, off);
    }
    // layer-1 output (fp32, all lanes redundant across qw): v_c = relu(a_c/s + b[4*fl+c])
    const float v0 = fmaxf(a0 / s + b[4 * fl], 0.f);
    const float v1 = fmaxf(a1 / s + b[4 * fl + 1], 0.f);
    const float v2 = fmaxf(a2 / s + b[4 * fl + 2], 0.f);
    const float v3 = fmaxf(a3 / s + b[4 * fl + 3], 0.f);
    // fused layer-2 transform: acc[lane] = sum_i h[i] * W2[i][lane], h[i] on lane i>>2 as v_{i&3}
    float acc = 0.f;
#pragma unroll 8
    for (int i = 0; i < 64; ++i) {
        float hi;
        if ((i & 3) == 0) hi = __shfl(v0, i >> 2);
        else if ((i & 3) == 1) hi = __shfl(v1, i >> 2);
        else if ((i & 3) == 2) hi = __shfl(v2, i >> 2);
        else hi = __shfl(v3, i >> 2);
        acc = fmaf(hi, W2[i * 64 + lane], acc);
    }
    float s2 = acc * av_s2[lane], d2 = acc * av_d2[lane];
#pragma unroll
    for (int off = 32; off; off >>= 1) { s2 += __shfl_xor(s2, off); d2 += __shfl_xor(d2, off); }
    if (lane == 0) { as_v2[n] = s2; ad_v2[n] = d2; }
    const float nb = __shfl(acc, lane | 1);
    if (!(lane & 1)) hbf2[(size_t)n * 32 + (lane >> 1)] = pack2(acc, nb);
}

// ---------------- GAT2: softmax-gather, bf16 output ----------------
__global__ __launch_bounds__(256) void k_gat2(
    const int* __restrict__ rowptr, const int* __restrict__ srcp, const float* __restrict__ asp,
    const unsigned* __restrict__ hbf, const float* __restrict__ as_v, const float* __restrict__ ad_v,
    const float* __restrict__ b, unsigned* __restrict__ outbf)
{
    const int n = (blockIdx.x * 256 + threadIdx.x) >> 6;
    if (n >= NN) return;
    const int lane = threadIdx.x & 63;
    const int fl = lane & 15, qw = lane >> 4;
    const int r0 = rowptr[n], r1 = rowptr[n + 1];
    const float adn = ad_v[n];
    const float l_self = lrelu(as_v[n] + adn);
    float m = l_self;
    for (int j = r0 + lane; j < r1; j += 64)
        m = fmaxf(m, lrelu(asp[j] + adn));
#pragma unroll
    for (int off = 32; off; off >>= 1) m = fmaxf(m, __shfl_xor(m, off));
    float s = 0.f;
    for (int j = r0 + lane; j < r1; j += 64)
        s += expf(lrelu(asp[j] + adn) - m);
#pragma unroll
    for (int off = 32; off; off >>= 1) s += __shfl_xor(s, off);
    const float w_self = expf(l_self - m);
    s += w_self;
    float a0 = 0.f, a1 = 0.f, a2 = 0.f, a3 = 0.f;
    if (qw == 0) {
        const uint2 hv = *(const uint2*)(hbf + (size_t)n * 32 + fl * 2);
        a0 = w_self * bf2f((unsigned short)(hv.x & 0xffff));
        a1 = w_self * bf2f((unsigned short)(hv.x >> 16));
        a2 = w_self * bf2f((unsigned short)(hv.y & 0xffff));
        a3 = w_self * bf2f((unsigned short)(hv.y >> 16));
    }
    for (int j = r0 + qw; j < r1; j += 4) {
        const int sn = srcp[j];
        const float w = expf(lrelu(asp[j] + adn) - m);
        const uint2 hv = *(const uint2*)(hbf + (size_t)sn * 32 + fl * 2);
        a0 = fmaf(w, bf2f((unsigned short)(hv.x & 0xffff)), a0);
        a1 = fmaf(w, bf2f((unsigned short)(hv.x >> 16)), a1);
        a2 = fmaf(w, bf2f((unsigned short)(hv.y & 0xffff)), a2);
        a3 = fmaf(w, bf2f((unsigned short)(hv.y >> 16)), a3);
    }
#pragma unroll
    for (int off = 16; off <= 32; off <<= 1) {
        a0 += __shfl_xor(a0, off);
        a1 += __shfl_xor(a1, off);
        a2 += __shfl_xor(a2, off);
        a3 += __shfl_xor(a3, off);
    }
    if (qw == 0) {
        const float v0 = fmaxf(a0 / s + b[4 * fl], 0.f);
        const float v1 = fmaxf(a1 / s + b[4 * fl + 1], 0.f);
        const float v2 = fmaxf(a2 / s + b[4 * fl + 2], 0.f);
        const float v3 = fmaxf(a3 / s + b[4 * fl + 3], 0.f);
        *(uint2*)(outbf + (size_t)n * 32 + fl * 2) = make_uint2(pack2(v0, v1), pack2(v2, v3));
    }
}

// ---------------- global mean pool (bf16 input) ----------------
__global__ __launch_bounds__(256) void k_pool1(
    const unsigned* __restrict__ hbf, const int* __restrict__ batch,
    float* __restrict__ gsum, float* __restrict__ gcnt)
{
    __shared__ float ls[NG * 64];
    __shared__ float lc[NG];
    for (int j = threadIdx.x; j < NG * 64; j += 256) ls[j] = 0.f;
    if (threadIdx.x < NG) lc[threadIdx.x] = 0.f;
    __syncthreads();
    const int base = blockIdx.x * 512;
    for (int idx = threadIdx.x; idx < 512 * 32; idx += 256) {
        const int nl = idx >> 5, f2 = idx & 31;
        const int n = base + nl;
        if (n < NN) {
            const int g = batch[n];
            const unsigned hv = hbf[(size_t)n * 32 + f2];
            atomicAdd(&ls[g * 64 + 2 * f2], bf2f((unsigned short)(hv & 0xffff)));
            atomicAdd(&ls[g * 64 + 2 * f2 + 1], bf2f((unsigned short)(hv >> 16)));
            if (f2 == 0) atomicAdd(&lc[g], 1.f);
        }
    }
    __syncthreads();
    for (int j = threadIdx.x; j < NG * 64; j += 256) atomicAdd(&gsum[j], ls[j]);
    if (threadIdx.x < NG) atomicAdd(&gcnt[threadIdx.x], lc[threadIdx.x]);
}

__global__ __launch_bounds__(256) void k_pool2(
    const float* __restrict__ gsum, const float* __restrict__ gcnt, float* __restrict__ out)
{
    const int idx = blockIdx.x * 256 + threadIdx.x;
    if (idx >= NG * 64) return;
    out[idx] = gsum[idx] / fmaxf(gcnt[idx >> 6], 1.f);
}

extern "C" void kernel_launch(void* const* d_in, const int* in_sizes, int n_in,
                              void* d_out, int out_size, void* d_ws, size_t ws_size,
                              hipStream_t stream)
{
    const float* x     = (const float*)d_in[0];
    const float* ea    = (const float*)d_in[1];
    const int*   ei    = (const int*)d_in[2];
    const int*   batch = (const int*)d_in[3];
    const float* w1 = (const float*)d_in[4];   const float* b1 = (const float*)d_in[5];
    const float* w2 = (const float*)d_in[6];   const float* b2 = (const float*)d_in[7];
    const float* w3 = (const float*)d_in[8];   const float* b3 = (const float*)d_in[9];
    const float* rw = (const float*)d_in[10];  const float* cb = (const float*)d_in[11];
    const float* g1w  = (const float*)d_in[12]; const float* g1as = (const float*)d_in[13];
    const float* g1ad = (const float*)d_in[14]; const float* g1b  = (const float*)d_in[15];
    const float* g2w  = (const float*)d_in[16]; const float* g2as = (const float*)d_in[17];
    const float* g2ad = (const float*)d_in[18]; const float* g2b  = (const float*)d_in[19];
    const int* src = ei;
    const int* dst = ei + NE;
    float* out = (float*)d_out;
    (void)in_sizes; (void)n_in; (void)out_size; (void)ws_size;

    char* ws = (char*)d_ws;
    size_t off = 0;
    auto alloc = [&](size_t bytes) -> char* {
        char* p = ws + off;
        off += (bytes + 255) & ~(size_t)255;
        return p;
    };
    int*  deg    = (int*)alloc((size_t)NN * 4);
    int*  cursor = (int*)alloc((size_t)NN * 4);
    int*  rowptr = (int*)alloc((size_t)(NN + 1) * 4);
    int*  bsum   = (int*)alloc((size_t)NSB * 4);
    int*  eid    = (int*)alloc((size_t)NE * 4);
    int*  srcp   = (int*)alloc((size_t)NE * 4);
    float* asp   = (float*)alloc((size_t)NE * 4);
    unsigned short* w3t_g = (unsigned short*)alloc((size_t)64 * 512 * 2);
    unsigned short* w2t_g = (unsigned short*)alloc((size_t)64 * 128 * 2);
    unsigned short* w1p_g = (unsigned short*)alloc((size_t)128 * 16 * 2);
    unsigned short* b3t_g = (unsigned short*)alloc((size_t)512 * 2);
    unsigned short* msg   = (unsigned short*)alloc((size_t)NE * 32 * 2);  // 25.6 MB
    unsigned* hT  = (unsigned*)alloc((size_t)NN * 32 * 4);   // layer-1 transformed, bf16 packed
    unsigned* hT2 = (unsigned*)alloc((size_t)NN * 32 * 4);   // layer-2 transformed, bf16 packed
    unsigned* hD  = (unsigned*)alloc((size_t)NN * 32 * 4);   // GAT2 output, bf16 packed
    float* as_v  = (float*)alloc((size_t)NN * 4);
    float* ad_v  = (float*)alloc((size_t)NN * 4);
    float* as_v2 = (float*)alloc((size_t)NN * 4);
    float* ad_v2 = (float*)alloc((size_t)NN * 4);
    float* gsum = (float*)alloc((size_t)NG * 64 * 4);
    float* gcnt = (float*)alloc((size_t)NG * 4);

    hipMemsetAsync(deg, 0, (size_t)NN * 4, stream);
    hipMemsetAsync(gsum, 0, (size_t)NG * 64 * 4, stream);
    hipMemsetAsync(gcnt, 0, (size_t)NG * 4, stream);

    // CSR build
    k_hist<<<(NE + 255) / 256, 256, 0, stream>>>(dst, deg);
    k_bsum<<<NSB, 256, 0, stream>>>(deg, bsum);
    k_scan2<<<NSB, 256, 0, stream>>>(deg, bsum, rowptr, cursor);
    k_perm<<<(NE + 255) / 256, 256, 0, stream>>>(dst, src, cursor, eid, srcp);

    // NNConv (fused, all-MFMA, 16 waves/block)
    k_wprep<<<(64 * 512 + 255) / 256, 256, 0, stream>>>(w3, w2, w1, b1, b3,
                                                        w3t_g, w2t_g, w1p_g, b3t_g);
    k_fused<<<FUSED_GRID, 1024, 0, stream>>>(ea, w1p_g, w2t_g, b2, w3t_g, b3t_g, src, x, msg);

    // agg + root + GAT1 transform (fused)
    k_aggt<<<(NN * 64 + 255) / 256, 256, 0, stream>>>(msg, rowptr, eid, x, rw, cb,
                                                      g1w, g1as, g1ad, hT, as_v, ad_v);
    // GAT layer 1 (+ fused layer-2 transform)
    k_easrc<<<(NE + 255) / 256, 256, 0, stream>>>(srcp, as_v, asp);
    k_gat1<<<(NN * 64 + 255) / 256, 256, 0, stream>>>(rowptr, srcp, asp, hT, as_v, ad_v, g1b,
                                                      g2w, g2as, g2ad, hT2, as_v2, ad_v2);
    // GAT layer 2
    k_easrc<<<(NE + 255) / 256, 256, 0, stream>>>(srcp, as_v2, asp);
    k_gat2<<<(NN * 64 + 255) / 256, 256, 0, stream>>>(rowptr, srcp, asp, hT2, as_v2, ad_v2, g2b, hD);

    // pool
    k_pool1<<<(NN + 511) / 512, 256, 0, stream>>>(hD, batch, gsum, gcnt);
    k_pool2<<<(NG * 64 + 255) / 256, 256, 0, stream>>>(gsum, gcnt, out);
}

// Round 13
// 315.624 us; speedup vs baseline: 1.3268x; 1.3268x over previous
//
#include <hip/hip_runtime.h>

#define NN 50000
#define NE 400000
#define NG 32
#define SLOPE 0.2f
#define NSB ((NN + 255) / 256)   // 196 scan blocks

typedef __attribute__((ext_vector_type(4))) float f32x4;
typedef __attribute__((ext_vector_type(16))) float f32x16;
typedef __attribute__((ext_vector_type(8))) short s16x8;

__device__ __forceinline__ float lrelu(float v) { return v > 0.f ? v : SLOPE * v; }
__device__ __forceinline__ unsigned short f2bf(float f) {
    union { float f; unsigned u; } c; c.f = f;
    unsigned r = c.u + 0x7fffu + ((c.u >> 16) & 1u);
    return (unsigned short)(r >> 16);
}
__device__ __forceinline__ float bf2f(unsigned short b) {
    union { unsigned u; float f; } c; c.u = ((unsigned)b) << 16; return c.f;
}
__device__ __forceinline__ unsigned pack2(float a, float b) {
    return (unsigned)f2bf(a) | ((unsigned)f2bf(b) << 16);
}
__device__ __forceinline__ uint2 pack_bf4(float a, float b, float c, float d) {
    uint2 u;
    u.x = pack2(a, b);
    u.y = pack2(c, d);
    return u;
}

// ---------------- CSR build ----------------
__global__ __launch_bounds__(256) void k_hist(const int* __restrict__ dst, int* __restrict__ deg) {
    int e = blockIdx.x * 256 + threadIdx.x;
    if (e < NE) atomicAdd(&deg[dst[e]], 1);
}

__global__ __launch_bounds__(256) void k_bsum(const int* __restrict__ deg, int* __restrict__ bsum) {
    __shared__ int ls[256];
    const int t = threadIdx.x;
    const int idx = blockIdx.x * 256 + t;
    ls[t] = (idx < NN) ? deg[idx] : 0;
    __syncthreads();
#pragma unroll
    for (int off = 128; off; off >>= 1) {
        if (t < off) ls[t] += ls[t + off];
        __syncthreads();
    }
    if (t == 0) bsum[blockIdx.x] = ls[0];
}

__global__ __launch_bounds__(256) void k_scan2(const int* __restrict__ deg,
                                               const int* __restrict__ bsum,
                                               int* __restrict__ rowptr, int* __restrict__ cursor) {
    __shared__ int lb[256];
    __shared__ int ls[256];
    const int t = threadIdx.x, b = blockIdx.x;
    lb[t] = (t < NSB && t < b) ? bsum[t] : 0;
    const int idx = b * 256 + t;
    const int v = (idx < NN) ? deg[idx] : 0;
    ls[t] = v;
    __syncthreads();
#pragma unroll
    for (int off = 128; off; off >>= 1) {
        if (t < off) lb[t] += lb[t + off];
        __syncthreads();
    }
#pragma unroll
    for (int off = 1; off < 256; off <<= 1) {
        int u = (t >= off) ? ls[t - off] : 0;
        __syncthreads();
        ls[t] += u;
        __syncthreads();
    }
    if (idx < NN) {
        const int run = lb[0] + ls[t] - v;
        rowptr[idx] = run;
        cursor[idx] = run;
    }
    if (b == 0 && t == 0) rowptr[NN] = NE;
}

__global__ __launch_bounds__(256) void k_perm(const int* __restrict__ dst, const int* __restrict__ src,
                                              int* __restrict__ cursor, int* __restrict__ eid,
                                              int* __restrict__ srcp) {
    int e = blockIdx.x * 256 + threadIdx.x;
    if (e < NE) {
        int p = atomicAdd(&cursor[dst[e]], 1);
        eid[p] = e;
        srcp[p] = src[e];
    }
}

// ---------------- one-time weight prep ----------------
__global__ __launch_bounds__(256) void k_wprep(const float* __restrict__ w3,
                                               const float* __restrict__ w2,
                                               const float* __restrict__ w1,
                                               const float* __restrict__ b1,
                                               const float* __restrict__ b3,
                                               unsigned short* __restrict__ w3t_g,
                                               unsigned short* __restrict__ w2t_g,
                                               unsigned short* __restrict__ w1p_g,
                                               unsigned short* __restrict__ b3t_g) {
    const int v = blockIdx.x * 256 + threadIdx.x;
    if (v < 64 * 512) {
        const int k = v >> 9, n = v & 511;
        const int byte = (n << 7) | ((k << 1) ^ ((n & 7) << 4));
        *(unsigned short*)((char*)w3t_g + byte) = f2bf(w3[v]);
    }
    if (v < 64 * 128) {
        const int o = v & 63, slot = v >> 6;
        const int ks = slot >> 4, lg2 = (slot >> 3) & 1, j = slot & 7;
        const int kp = (ks >> 1) * 32 + (j & 3) + 8 * (j >> 2) + 16 * (ks & 1) + 4 * lg2;
        const int byte = (o << 8) | ((slot << 1) ^ ((o & 7) << 4));
        *(unsigned short*)((char*)w2t_g + byte) = f2bf(w2[kp * 64 + o]);
    }
    if (v < 128 * 16) {
        const int j = v >> 4, k = v & 15;
        float val = (k < 3) ? w1[k * 128 + j] : (k == 3 ? b1[j] : 0.f);
        w1p_g[v] = f2bf(val);
    }
    if (v < 512) {
        const int i = v >> 5, o = v & 31;
        b3t_g[o * 16 + i] = f2bf(b3[v]);
    }
}

// ---------------- fused NNConv, all-MFMA, 32 edges/chunk (R11 512-thread version) ----------
#define FUSED_GRID 256
#define NCHUNK (NE / 32)
__global__ __launch_bounds__(512, 1) void k_fused(
    const float* __restrict__ ea,
    const unsigned short* __restrict__ w1p_g,
    const unsigned short* __restrict__ w2t_g, const float* __restrict__ b2,
    const unsigned short* __restrict__ w3t_g, const unsigned short* __restrict__ b3t_g,
    const int* __restrict__ src, const float* __restrict__ x,
    unsigned short* __restrict__ msg)
{
    __shared__ __align__(16) unsigned short w3t[512 * 64];
    __shared__ __align__(16) unsigned short w2t[64 * 128];
    __shared__ __align__(16) unsigned short w1p[128 * 16];
    __shared__ __align__(16) unsigned short b3t[512];
    __shared__ __align__(16) float b2s[64];
    __shared__ __align__(16) unsigned slab[8][1024];

    const int t = threadIdx.x;
    {
        const uint4* g = (const uint4*)w3t_g;
        uint4* l = (uint4*)w3t;
        for (int v = t; v < 4096; v += 512) l[v] = g[v];
        const uint4* g2 = (const uint4*)w2t_g;
        uint4* l2 = (uint4*)w2t;
        for (int v = t; v < 1024; v += 512) l2[v] = g2[v];
    }
    if (t < 256) ((uint4*)w1p)[t] = ((const uint4*)w1p_g)[t];
    if (t < 64)  ((uint4*)b3t)[t] = ((const uint4*)b3t_g)[t];
    if (t < 64)  b2s[t] = b2[t];
    __syncthreads();

    const int wid = t >> 6, lane = t & 63;
    const int l31 = lane & 31, lg2 = lane >> 5;
    char* sw = (char*)slab[wid];
    const int swz = (l31 & 7) << 4;

    s16x8 w1pf[4];
#pragma unroll
    for (int n = 0; n < 4; ++n)
        w1pf[n] = *(const s16x8*)((const char*)w1p + ((n * 32 + l31) << 5) + lg2 * 16);
    s16x8 b3f = *(const s16x8*)((const char*)b3t + (l31 << 5) + lg2 * 16);

    for (int chunk = blockIdx.x * 8 + wid; chunk < NCHUNK; chunk += FUSED_GRID * 8) {
        const int e = chunk * 32 + l31;
        const int sn = src[e];
        const f32x4* __restrict__ xp = (const f32x4*)(x + (size_t)sn * 16);
        f32x4 x0 = xp[0], x1 = xp[1], x2 = xp[2], x3 = xp[3];
        const float ea0 = ea[e * 3], ea1 = ea[e * 3 + 1], ea2 = ea[e * 3 + 2];

        // ---- L1: 4 MFMAs, pack D into L2 B-fragments ----
        s16x8 eb = (s16x8){0, 0, 0, 0, 0, 0, 0, 0};
        if (lg2 == 0) {
            eb[0] = (short)f2bf(ea0); eb[1] = (short)f2bf(ea1);
            eb[2] = (short)f2bf(ea2); eb[3] = (short)0x3F80;  // 1.0
        }
        s16x8 hb[8];
#pragma unroll
        for (int n = 0; n < 4; ++n) {
            f32x16 d = {0.f};
            d = __builtin_amdgcn_mfma_f32_32x32x16_bf16(w1pf[n], eb, d, 0, 0, 0);
#pragma unroll
            for (int s = 0; s < 2; ++s)
#pragma unroll
                for (int j = 0; j < 8; ++j)
                    hb[2 * n + s][j] = (short)f2bf(fmaxf(d[(j & 3) + 4 * (j >> 2) + 8 * s], 0.f));
        }

        // ---- L2: h2 = relu(w2t @ h1 + b2), 16 MFMAs; b2 added at pack from LDS ----
        asm volatile("s_waitcnt lgkmcnt(0)" ::: "memory");
#pragma unroll
        for (int nblk = 0; nblk < 2; ++nblk) {
            f32x16 a2 = {0.f};
            const char* __restrict__ w2row = (const char*)w2t + ((nblk * 32 + l31) << 8);
#pragma unroll
            for (int ks = 0; ks < 8; ++ks) {
                s16x8 a = *(const s16x8*)(w2row + ((ks * 32 + lg2 * 16) ^ swz));
                a2 = __builtin_amdgcn_mfma_f32_32x32x16_bf16(a, hb[ks], a2, 0, 0, 0);
            }
#pragma unroll
            for (int rh = 0; rh < 4; ++rh) {
                const f32x4 bv = *(const f32x4*)(b2s + nblk * 32 + rh * 8 + lg2 * 4);
                const int kb = nblk * 64 + rh * 16 + lg2 * 8;
                *(uint2*)(sw + l31 * 128 + (kb ^ swz)) =
                    pack_bf4(fmaxf(a2[rh * 4] + bv[0], 0.f), fmaxf(a2[rh * 4 + 1] + bv[1], 0.f),
                             fmaxf(a2[rh * 4 + 2] + bv[2], 0.f), fmaxf(a2[rh * 4 + 3] + bv[3], 0.f));
            }
        }
        asm volatile("s_waitcnt lgkmcnt(0)" ::: "memory");

        s16x8 wb[4];
#pragma unroll
        for (int ks = 0; ks < 4; ++ks)
            wb[ks] = *(const s16x8*)(sw + l31 * 128 + ((ks * 32 + lg2 * 16) ^ swz));

        s16x8 xbf;
        {
            f32x4 a0 = lg2 ? x2 : x0, a1 = lg2 ? x3 : x1;
#pragma unroll
            for (int i = 0; i < 4; ++i) {
                xbf[i] = (short)f2bf(a0[i]);
                xbf[i + 4] = (short)f2bf(a1[i]);
            }
        }
        f32x16 p = {0.f};
        p = __builtin_amdgcn_mfma_f32_32x32x16_bf16(b3f, xbf, p, 0, 0, 0);

#pragma unroll
        for (int nblk = 0; nblk < 16; ++nblk) {
            const char* __restrict__ arow = (const char*)w3t + ((nblk * 32 + l31) << 7);
            f32x16 d = {0.f};
#pragma unroll
            for (int ks = 0; ks < 4; ++ks) {
                s16x8 a = *(const s16x8*)(arow + ((ks * 32 + lg2 * 16) ^ swz));
                d = __builtin_amdgcn_mfma_f32_32x32x16_bf16(a, wb[ks], d, 0, 0, 0);
            }
            const float xs = (nblk < 4 ? x0 : nblk < 8 ? x1 : nblk < 12 ? x2 : x3)[nblk & 3];
#pragma unroll
            for (int r = 0; r < 16; ++r) p[r] = fmaf(xs, d[r], p[r]);
        }

        asm volatile("s_waitcnt lgkmcnt(0)" ::: "memory");
#pragma unroll
        for (int rh = 0; rh < 4; ++rh) {
            const int ob = rh * 16 + lg2 * 8;
            *(uint2*)(sw + l31 * 64 + (ob ^ ((l31 & 7) << 3))) =
                pack_bf4(p[rh * 4], p[rh * 4 + 1], p[rh * 4 + 2], p[rh * 4 + 3]);
        }
        asm volatile("s_waitcnt lgkmcnt(0)" ::: "memory");
#pragma unroll
        for (int q = 0; q < 2; ++q) {
            const int er = (lane >> 2) + q * 16;
            const int off = (lane & 3) * 16;
            const int s8 = (er & 7) << 3;
            uint2 a = *(const uint2*)(sw + er * 64 + (off ^ s8));
            uint2 b = *(const uint2*)(sw + er * 64 + ((off + 8) ^ s8));
            *(uint4*)((char*)msg + (size_t)chunk * 2048 + q * 1024 + lane * 16) =
                make_uint4(a.x, a.y, b.x, b.y);
        }
    }
}

// ---------------- fused: agg (CSR gather) + root + GAT1 node transform ----------------
__global__ __launch_bounds__(256) void k_aggt(
    const unsigned short* __restrict__ msg, const int* __restrict__ rowptr,
    const int* __restrict__ eid, const float* __restrict__ x,
    const float* __restrict__ rw, const float* __restrict__ cb,
    const float* __restrict__ W, const float* __restrict__ av_s, const float* __restrict__ av_d,
    unsigned* __restrict__ hbf, float* __restrict__ as_v, float* __restrict__ ad_v)
{
    const int n = (blockIdx.x * 256 + threadIdx.x) >> 6;
    if (n >= NN) return;
    const int lane = threadIdx.x & 63;
    const int half = lane >> 5, o = lane & 31;
    const int r0 = rowptr[n], r1 = rowptr[n + 1];
    float agg = 0.f;
    for (int j = r0 + half; j < r1; j += 2)
        agg += bf2f(msg[(size_t)eid[j] * 32 + o]);
    agg += __shfl_xor(agg, 32);
    const float* __restrict__ xr = x + (size_t)n * 16;
    float root = cb[o];
#pragma unroll
    for (int i = 0; i < 16; ++i) root = fmaf(xr[i], rw[i * 32 + o], root);
    const float h1v = fmaxf(agg + root, 0.f);
    float acc = 0.f;
#pragma unroll 8
    for (int i = 0; i < 32; ++i)
        acc = fmaf(__shfl(h1v, i), W[i * 64 + lane], acc);
    float s = acc * av_s[lane], d = acc * av_d[lane];
#pragma unroll
    for (int off = 32; off; off >>= 1) { s += __shfl_xor(s, off); d += __shfl_xor(d, off); }
    if (lane == 0) { as_v[n] = s; ad_v[n] = d; }
    const float nb = __shfl(acc, lane | 1);
    if (!(lane & 1)) hbf[(size_t)n * 32 + (lane >> 1)] = pack2(acc, nb);
}

// asp[j] = as_v[srcp[j]]
__global__ __launch_bounds__(256) void k_easrc(const int* __restrict__ srcp,
                                               const float* __restrict__ as_v,
                                               float* __restrict__ asp) {
    int j = blockIdx.x * 256 + threadIdx.x;
    if (j < NE) asp[j] = as_v[srcp[j]];
}

// ---------------- GAT1: softmax-gather + fused layer-2 node transform ----------------
__global__ __launch_bounds__(256) void k_gat1(
    const int* __restrict__ rowptr, const int* __restrict__ srcp, const float* __restrict__ asp,
    const unsigned* __restrict__ hbf, const float* __restrict__ as_v, const float* __restrict__ ad_v,
    const float* __restrict__ b,
    const float* __restrict__ W2, const float* __restrict__ av_s2, const float* __restrict__ av_d2,
    unsigned* __restrict__ hbf2, float* __restrict__ as_v2, float* __restrict__ ad_v2)
{
    const int n = (blockIdx.x * 256 + threadIdx.x) >> 6;
    if (n >= NN) return;
    const int lane = threadIdx.x & 63;
    const int fl = lane & 15, qw = lane >> 4;
    const int r0 = rowptr[n], r1 = rowptr[n + 1];
    const float adn = ad_v[n];
    const float l_self = lrelu(as_v[n] + adn);
    float m = l_self;
    for (int j = r0 + lane; j < r1; j += 64)
        m = fmaxf(m, lrelu(asp[j] + adn));
#pragma unroll
    for (int off = 32; off; off >>= 1) m = fmaxf(m, __shfl_xor(m, off));
    float s = 0.f;
    for (int j = r0 + lane; j < r1; j += 64)
        s += expf(lrelu(asp[j] + adn) - m);
#pragma unroll
    for (int off = 32; off; off >>= 1) s += __shfl_xor(s, off);
    const float w_self = expf(l_self - m);
    s += w_self;
    float a0 = 0.f, a1 = 0.f, a2 = 0.f, a3 = 0.f;
    if (qw == 0) {
        const uint2 hv = *(const uint2*)(hbf + (size_t)n * 32 + fl * 2);
        a0 = w_self * bf2f((unsigned short)(hv.x & 0xffff));
        a1 = w_self * bf2f((unsigned short)(hv.x >> 16));
        a2 = w_self * bf2f((unsigned short)(hv.y & 0xffff));
        a3 = w_self * bf2f((unsigned short)(hv.y >> 16));
    }
    for (int j = r0 + qw; j < r1; j += 4) {
        const int sn = srcp[j];
        const float w = expf(lrelu(asp[j] + adn) - m);
        const uint2 hv = *(const uint2*)(hbf + (size_t)sn * 32 + fl * 2);
        a0 = fmaf(w, bf2f((unsigned short)(hv.x & 0xffff)), a0);
        a1 = fmaf(w, bf2f((unsigned short)(hv.x >> 16)), a1);
        a2 = fmaf(w, bf2f((unsigned short)(hv.y & 0xffff)), a2);
        a3 = fmaf(w, bf2f((unsigned short)(hv.y >> 16)), a3);
    }
#pragma unroll
    for (int off = 16; off <= 32; off <<= 1) {
        a0 += __shfl_xor(a0, off);
        a1 += __shfl_xor(a1, off);
        a2 += __shfl_xor(a2, off);
        a3 += __shfl_xor(a3, off);
    }
    const float v0 = fmaxf(a0 / s + b[4 * fl], 0.f);
    const float v1 = fmaxf(a1 / s + b[4 * fl + 1], 0.f);
    const float v2 = fmaxf(a2 / s + b[4 * fl + 2], 0.f);
    const float v3 = fmaxf(a3 / s + b[4 * fl + 3], 0.f);
    float acc = 0.f;
#pragma unroll 8
    for (int i = 0; i < 64; ++i) {
        float hi;
        if ((i & 3) == 0) hi = __shfl(v0, i >> 2);
        else if ((i & 3) == 1) hi = __shfl(v1, i >> 2);
        else if ((i & 3) == 2) hi = __shfl(v2, i >> 2);
        else hi = __shfl(v3, i >> 2);
        acc = fmaf(hi, W2[i * 64 + lane], acc);
    }
    float s2 = acc * av_s2[lane], d2 = acc * av_d2[lane];
#pragma unroll
    for (int off = 32; off; off >>= 1) { s2 += __shfl_xor(s2, off); d2 += __shfl_xor(d2, off); }
    if (lane == 0) { as_v2[n] = s2; ad_v2[n] = d2; }
    const float nb = __shfl(acc, lane | 1);
    if (!(lane & 1)) hbf2[(size_t)n * 32 + (lane >> 1)] = pack2(acc, nb);
}

// ---------------- GAT2: softmax-gather, bf16 output ----------------
__global__ __launch_bounds__(256) void k_gat2(
    const int* __restrict__ rowptr, const int* __restrict__ srcp, const float* __restrict__ asp,
    const unsigned* __restrict__ hbf, const float* __restrict__ as_v, const float* __restrict__ ad_v,
    const float* __restrict__ b, unsigned* __restrict__ outbf)
{
    const int n = (blockIdx.x * 256 + threadIdx.x) >> 6;
    if (n >= NN) return;
    const int lane = threadIdx.x & 63;
    const int fl = lane & 15, qw = lane >> 4;
    const int r0 = rowptr[n], r1 = rowptr[n + 1];
    const float adn = ad_v[n];
    const float l_self = lrelu(as_v[n] + adn);
    float m = l_self;
    for (int j = r0 + lane; j < r1; j += 64)
        m = fmaxf(m, lrelu(asp[j] + adn));
#pragma unroll
    for (int off = 32; off; off >>= 1) m = fmaxf(m, __shfl_xor(m, off));
    float s = 0.f;
    for (int j = r0 + lane; j < r1; j += 64)
        s += expf(lrelu(asp[j] + adn) - m);
#pragma unroll
    for (int off = 32; off; off >>= 1) s += __shfl_xor(s, off);
    const float w_self = expf(l_self - m);
    s += w_self;
    float a0 = 0.f, a1 = 0.f, a2 = 0.f, a3 = 0.f;
    if (qw == 0) {
        const uint2 hv = *(const uint2*)(hbf + (size_t)n * 32 + fl * 2);
        a0 = w_self * bf2f((unsigned short)(hv.x & 0xffff));
        a1 = w_self * bf2f((unsigned short)(hv.x >> 16));
        a2 = w_self * bf2f((unsigned short)(hv.y & 0xffff));
        a3 = w_self * bf2f((unsigned short)(hv.y >> 16));
    }
    for (int j = r0 + qw; j < r1; j += 4) {
        const int sn = srcp[j];
        const float w = expf(lrelu(asp[j] + adn) - m);
        const uint2 hv = *(const uint2*)(hbf + (size_t)sn * 32 + fl * 2);
        a0 = fmaf(w, bf2f((unsigned short)(hv.x & 0xffff)), a0);
        a1 = fmaf(w, bf2f((unsigned short)(hv.x >> 16)), a1);
        a2 = fmaf(w, bf2f((unsigned short)(hv.y & 0xffff)), a2);
        a3 = fmaf(w, bf2f((unsigned short)(hv.y >> 16)), a3);
    }
#pragma unroll
    for (int off = 16; off <= 32; off <<= 1) {
        a0 += __shfl_xor(a0, off);
        a1 += __shfl_xor(a1, off);
        a2 += __shfl_xor(a2, off);
        a3 += __shfl_xor(a3, off);
    }
    if (qw == 0) {
        const float v0 = fmaxf(a0 / s + b[4 * fl], 0.f);
        const float v1 = fmaxf(a1 / s + b[4 * fl + 1], 0.f);
        const float v2 = fmaxf(a2 / s + b[4 * fl + 2], 0.f);
        const float v3 = fmaxf(a3 / s + b[4 * fl + 3], 0.f);
        *(uint2*)(outbf + (size_t)n * 32 + fl * 2) = make_uint2(pack2(v0, v1), pack2(v2, v3));
    }
}

// ---------------- global mean pool (bf16 input) ----------------
__global__ __launch_bounds__(256) void k_pool1(
    const unsigned* __restrict__ hbf, const int* __restrict__ batch,
    float* __restrict__ gsum, float* __restrict__ gcnt)
{
    __shared__ float ls[NG * 64];
    __shared__ float lc[NG];
    for (int j = threadIdx.x; j < NG * 64; j += 256) ls[j] = 0.f;
    if (threadIdx.x < NG) lc[threadIdx.x] = 0.f;
    __syncthreads();
    const int base = blockIdx.x * 512;
    for (int idx = threadIdx.x; idx < 512 * 32; idx += 256) {
        const int nl = idx >> 5, f2 = idx & 31;
        const int n = base + nl;
        if (n < NN) {
            const int g = batch[n];
            const unsigned hv = hbf[(size_t)n * 32 + f2];
            atomicAdd(&ls[g * 64 + 2 * f2], bf2f((unsigned short)(hv & 0xffff)));
            atomicAdd(&ls[g * 64 + 2 * f2 + 1], bf2f((unsigned short)(hv >> 16)));
            if (f2 == 0) atomicAdd(&lc[g], 1.f);
        }
    }
    __syncthreads();
    for (int j = threadIdx.x; j < NG * 64; j += 256) atomicAdd(&gsum[j], ls[j]);
    if (threadIdx.x < NG) atomicAdd(&gcnt[threadIdx.x], lc[threadIdx.x]);
}

__global__ __launch_bounds__(256) void k_pool2(
    const float* __restrict__ gsum, const float* __restrict__ gcnt, float* __restrict__ out)
{
    const int idx = blockIdx.x * 256 + threadIdx.x;
    if (idx >= NG * 64) return;
    out[idx] = gsum[idx] / fmaxf(gcnt[idx >> 6], 1.f);
}

extern "C" void kernel_launch(void* const* d_in, const int* in_sizes, int n_in,
                              void* d_out, int out_size, void* d_ws, size_t ws_size,
                              hipStream_t stream)
{
    const float* x     = (const float*)d_in[0];
    const float* ea    = (const float*)d_in[1];
    const int*   ei    = (const int*)d_in[2];
    const int*   batch = (const int*)d_in[3];
    const float* w1 = (const float*)d_in[4];   const float* b1 = (const float*)d_in[5];
    const float* w2 = (const float*)d_in[6];   const float* b2 = (const float*)d_in[7];
    const float* w3 = (const float*)d_in[8];   const float* b3 = (const float*)d_in[9];
    const float* rw = (const float*)d_in[10];  const float* cb = (const float*)d_in[11];
    const float* g1w  = (const float*)d_in[12]; const float* g1as = (const float*)d_in[13];
    const float* g1ad = (const float*)d_in[14]; const float* g1b  = (const float*)d_in[15];
    const float* g2w  = (const float*)d_in[16]; const float* g2as = (const float*)d_in[17];
    const float* g2ad = (const float*)d_in[18]; const float* g2b  = (const float*)d_in[19];
    const int* src = ei;
    const int* dst = ei + NE;
    float* out = (float*)d_out;
    (void)in_sizes; (void)n_in; (void)out_size; (void)ws_size;

    char* ws = (char*)d_ws;
    size_t off = 0;
    auto alloc = [&](size_t bytes) -> char* {
        char* p = ws + off;
        off += (bytes + 255) & ~(size_t)255;
        return p;
    };
    int*  deg    = (int*)alloc((size_t)NN * 4);
    int*  cursor = (int*)alloc((size_t)NN * 4);
    int*  rowptr = (int*)alloc((size_t)(NN + 1) * 4);
    int*  bsum   = (int*)alloc((size_t)NSB * 4);
    int*  eid    = (int*)alloc((size_t)NE * 4);
    int*  srcp   = (int*)alloc((size_t)NE * 4);
    float* asp   = (float*)alloc((size_t)NE * 4);
    unsigned short* w3t_g = (unsigned short*)alloc((size_t)64 * 512 * 2);
    unsigned short* w2t_g = (unsigned short*)alloc((size_t)64 * 128 * 2);
    unsigned short* w1p_g = (unsigned short*)alloc((size_t)128 * 16 * 2);
    unsigned short* b3t_g = (unsigned short*)alloc((size_t)512 * 2);
    unsigned short* msg   = (unsigned short*)alloc((size_t)NE * 32 * 2);  // 25.6 MB
    unsigned* hT  = (unsigned*)alloc((size_t)NN * 32 * 4);
    unsigned* hT2 = (unsigned*)alloc((size_t)NN * 32 * 4);
    unsigned* hD  = (unsigned*)alloc((size_t)NN * 32 * 4);
    float* as_v  = (float*)alloc((size_t)NN * 4);
    float* ad_v  = (float*)alloc((size_t)NN * 4);
    float* as_v2 = (float*)alloc((size_t)NN * 4);
    float* ad_v2 = (float*)alloc((size_t)NN * 4);
    float* gsum = (float*)alloc((size_t)NG * 64 * 4);
    float* gcnt = (float*)alloc((size_t)NG * 4);

    hipMemsetAsync(deg, 0, (size_t)NN * 4, stream);
    hipMemsetAsync(gsum, 0, (size_t)NG * 64 * 4, stream);
    hipMemsetAsync(gcnt, 0, (size_t)NG * 4, stream);

    // CSR build
    k_hist<<<(NE + 255) / 256, 256, 0, stream>>>(dst, deg);
    k_bsum<<<NSB, 256, 0, stream>>>(deg, bsum);
    k_scan2<<<NSB, 256, 0, stream>>>(deg, bsum, rowptr, cursor);
    k_perm<<<(NE + 255) / 256, 256, 0, stream>>>(dst, src, cursor, eid, srcp);

    // NNConv (fused, all-MFMA, 512 threads / 128 VGPR)
    k_wprep<<<(64 * 512 + 255) / 256, 256, 0, stream>>>(w3, w2, w1, b1, b3,
                                                        w3t_g, w2t_g, w1p_g, b3t_g);
    k_fused<<<FUSED_GRID, 512, 0, stream>>>(ea, w1p_g, w2t_g, b2, w3t_g, b3t_g, src, x, msg);

    // agg + root + GAT1 transform (fused)
    k_aggt<<<(NN * 64 + 255) / 256, 256, 0, stream>>>(msg, rowptr, eid, x, rw, cb,
                                                      g1w, g1as, g1ad, hT, as_v, ad_v);
    // GAT layer 1 (+ fused layer-2 transform)
    k_easrc<<<(NE + 255) / 256, 256, 0, stream>>>(srcp, as_v, asp);
    k_gat1<<<(NN * 64 + 255) / 256, 256, 0, stream>>>(rowptr, srcp, asp, hT, as_v, ad_v, g1b,
                                                      g2w, g2as, g2ad, hT2, as_v2, ad_v2);
    // GAT layer 2
    k_easrc<<<(NE + 255) / 256, 256, 0, stream>>>(srcp, as_v2, asp);
    k_gat2<<<(NN * 64 + 255) / 256, 256, 0, stream>>>(rowptr, srcp, asp, hT2, as_v2, ad_v2, g2b, hD);

    // pool
    k_pool1<<<(NN + 511) / 512, 256, 0, stream>>>(hD, batch, gsum, gcnt);
    k_pool2<<<(NG * 64 + 255) / 256, 256, 0, stream>>>(gsum, gcnt, out);
}

// Round 14
// 311.119 us; speedup vs baseline: 1.3461x; 1.0145x over previous
//
#include <hip/hip_runtime.h>

#define NN 50000
#define NE 400000
#define NG 32
#define SLOPE 0.2f
#define NSB ((NN + 255) / 256)   // 196 scan blocks

typedef __attribute__((ext_vector_type(4))) float f32x4;
typedef __attribute__((ext_vector_type(16))) float f32x16;
typedef __attribute__((ext_vector_type(8))) short s16x8;

__device__ __forceinline__ float lrelu(float v) { return v > 0.f ? v : SLOPE * v; }
__device__ __forceinline__ unsigned short f2bf(float f) {
    union { float f; unsigned u; } c; c.f = f;
    unsigned r = c.u + 0x7fffu + ((c.u >> 16) & 1u);
    return (unsigned short)(r >> 16);
}
__device__ __forceinline__ float bf2f(unsigned short b) {
    union { unsigned u; float f; } c; c.u = ((unsigned)b) << 16; return c.f;
}
__device__ __forceinline__ unsigned pack2(float a, float b) {
    return (unsigned)f2bf(a) | ((unsigned)f2bf(b) << 16);
}
__device__ __forceinline__ uint2 pack_bf4(float a, float b, float c, float d) {
    uint2 u;
    u.x = pack2(a, b);
    u.y = pack2(c, d);
    return u;
}

// ---------------- CSR build ----------------
__global__ __launch_bounds__(256) void k_hist(const int* __restrict__ dst, int* __restrict__ deg) {
    int e = blockIdx.x * 256 + threadIdx.x;
    if (e < NE) atomicAdd(&deg[dst[e]], 1);
}

__global__ __launch_bounds__(256) void k_bsum(const int* __restrict__ deg, int* __restrict__ bsum) {
    __shared__ int ls[256];
    const int t = threadIdx.x;
    const int idx = blockIdx.x * 256 + t;
    ls[t] = (idx < NN) ? deg[idx] : 0;
    __syncthreads();
#pragma unroll
    for (int off = 128; off; off >>= 1) {
        if (t < off) ls[t] += ls[t + off];
        __syncthreads();
    }
    if (t == 0) bsum[blockIdx.x] = ls[0];
}

__global__ __launch_bounds__(256) void k_scan2(const int* __restrict__ deg,
                                               const int* __restrict__ bsum,
                                               int* __restrict__ rowptr, int* __restrict__ cursor) {
    __shared__ int lb[256];
    __shared__ int ls[256];
    const int t = threadIdx.x, b = blockIdx.x;
    lb[t] = (t < NSB && t < b) ? bsum[t] : 0;
    const int idx = b * 256 + t;
    const int v = (idx < NN) ? deg[idx] : 0;
    ls[t] = v;
    __syncthreads();
#pragma unroll
    for (int off = 128; off; off >>= 1) {
        if (t < off) lb[t] += lb[t + off];
        __syncthreads();
    }
#pragma unroll
    for (int off = 1; off < 256; off <<= 1) {
        int u = (t >= off) ? ls[t - off] : 0;
        __syncthreads();
        ls[t] += u;
        __syncthreads();
    }
    if (idx < NN) {
        const int run = lb[0] + ls[t] - v;
        rowptr[idx] = run;
        cursor[idx] = run;
    }
    if (b == 0 && t == 0) rowptr[NN] = NE;
}

__global__ __launch_bounds__(256) void k_perm(const int* __restrict__ dst, const int* __restrict__ src,
                                              int* __restrict__ cursor, int* __restrict__ eid,
                                              int* __restrict__ srcp) {
    int e = blockIdx.x * 256 + threadIdx.x;
    if (e < NE) {
        int p = atomicAdd(&cursor[dst[e]], 1);
        eid[p] = e;
        srcp[p] = src[e];
    }
}

// ---------------- one-time weight prep ----------------
__global__ __launch_bounds__(256) void k_wprep(const float* __restrict__ w3,
                                               const float* __restrict__ w2,
                                               const float* __restrict__ w1,
                                               const float* __restrict__ b1,
                                               const float* __restrict__ b3,
                                               unsigned short* __restrict__ w3t_g,
                                               unsigned short* __restrict__ w2t_g,
                                               unsigned short* __restrict__ w1p_g,
                                               unsigned short* __restrict__ b3t_g) {
    const int v = blockIdx.x * 256 + threadIdx.x;
    if (v < 64 * 512) {
        const int k = v >> 9, n = v & 511;
        const int byte = (n << 7) | ((k << 1) ^ ((n & 7) << 4));
        *(unsigned short*)((char*)w3t_g + byte) = f2bf(w3[v]);
    }
    if (v < 64 * 128) {
        const int o = v & 63, slot = v >> 6;
        const int ks = slot >> 4, lg2 = (slot >> 3) & 1, j = slot & 7;
        const int kp = (ks >> 1) * 32 + (j & 3) + 8 * (j >> 2) + 16 * (ks & 1) + 4 * lg2;
        const int byte = (o << 8) | ((slot << 1) ^ ((o & 7) << 4));
        *(unsigned short*)((char*)w2t_g + byte) = f2bf(w2[kp * 64 + o]);
    }
    if (v < 128 * 16) {
        const int j = v >> 4, k = v & 15;
        float val = (k < 3) ? w1[k * 128 + j] : (k == 3 ? b1[j] : 0.f);
        w1p_g[v] = f2bf(val);
    }
    if (v < 512) {
        const int i = v >> 5, o = v & 31;
        b3t_g[o * 16 + i] = f2bf(b3[v]);
    }
}

// ---------------- fused NNConv, all-MFMA, 32 edges/chunk, CSR-ordered msg output ----------
// R14: edges processed in CSR position order (e = eid[jpos], sn = srcp[jpos]); msg written
// linearly at jpos so k_aggt reads it as a pure stream. ea becomes a gathered 12B read
// (4.8MB L3-resident) hidden under the MFMA pipeline.
#define FUSED_GRID 256
#define NCHUNK (NE / 32)
__global__ __launch_bounds__(512, 1) void k_fused(
    const float* __restrict__ ea, const int* __restrict__ eid,
    const unsigned short* __restrict__ w1p_g,
    const unsigned short* __restrict__ w2t_g, const float* __restrict__ b2,
    const unsigned short* __restrict__ w3t_g, const unsigned short* __restrict__ b3t_g,
    const int* __restrict__ srcp, const float* __restrict__ x,
    unsigned short* __restrict__ msg)
{
    __shared__ __align__(16) unsigned short w3t[512 * 64];
    __shared__ __align__(16) unsigned short w2t[64 * 128];
    __shared__ __align__(16) unsigned short w1p[128 * 16];
    __shared__ __align__(16) unsigned short b3t[512];
    __shared__ __align__(16) float b2s[64];
    __shared__ __align__(16) unsigned slab[8][1024];

    const int t = threadIdx.x;
    {
        const uint4* g = (const uint4*)w3t_g;
        uint4* l = (uint4*)w3t;
        for (int v = t; v < 4096; v += 512) l[v] = g[v];
        const uint4* g2 = (const uint4*)w2t_g;
        uint4* l2 = (uint4*)w2t;
        for (int v = t; v < 1024; v += 512) l2[v] = g2[v];
    }
    if (t < 256) ((uint4*)w1p)[t] = ((const uint4*)w1p_g)[t];
    if (t < 64)  ((uint4*)b3t)[t] = ((const uint4*)b3t_g)[t];
    if (t < 64)  b2s[t] = b2[t];
    __syncthreads();

    const int wid = t >> 6, lane = t & 63;
    const int l31 = lane & 31, lg2 = lane >> 5;
    char* sw = (char*)slab[wid];
    const int swz = (l31 & 7) << 4;

    s16x8 w1pf[4];
#pragma unroll
    for (int n = 0; n < 4; ++n)
        w1pf[n] = *(const s16x8*)((const char*)w1p + ((n * 32 + l31) << 5) + lg2 * 16);
    s16x8 b3f = *(const s16x8*)((const char*)b3t + (l31 << 5) + lg2 * 16);

    for (int chunk = blockIdx.x * 8 + wid; chunk < NCHUNK; chunk += FUSED_GRID * 8) {
        const int jpos = chunk * 32 + l31;
        const int e = eid[jpos];
        const int sn = srcp[jpos];
        const f32x4* __restrict__ xp = (const f32x4*)(x + (size_t)sn * 16);
        f32x4 x0 = xp[0], x1 = xp[1], x2 = xp[2], x3 = xp[3];
        const float ea0 = ea[e * 3], ea1 = ea[e * 3 + 1], ea2 = ea[e * 3 + 2];

        // ---- L1: 4 MFMAs, pack D into L2 B-fragments ----
        s16x8 eb = (s16x8){0, 0, 0, 0, 0, 0, 0, 0};
        if (lg2 == 0) {
            eb[0] = (short)f2bf(ea0); eb[1] = (short)f2bf(ea1);
            eb[2] = (short)f2bf(ea2); eb[3] = (short)0x3F80;  // 1.0
        }
        s16x8 hb[8];
#pragma unroll
        for (int n = 0; n < 4; ++n) {
            f32x16 d = {0.f};
            d = __builtin_amdgcn_mfma_f32_32x32x16_bf16(w1pf[n], eb, d, 0, 0, 0);
#pragma unroll
            for (int s = 0; s < 2; ++s)
#pragma unroll
                for (int j = 0; j < 8; ++j)
                    hb[2 * n + s][j] = (short)f2bf(fmaxf(d[(j & 3) + 4 * (j >> 2) + 8 * s], 0.f));
        }

        // ---- L2: h2 = relu(w2t @ h1 + b2), 16 MFMAs; b2 added at pack from LDS ----
        asm volatile("s_waitcnt lgkmcnt(0)" ::: "memory");
#pragma unroll
        for (int nblk = 0; nblk < 2; ++nblk) {
            f32x16 a2 = {0.f};
            const char* __restrict__ w2row = (const char*)w2t + ((nblk * 32 + l31) << 8);
#pragma unroll
            for (int ks = 0; ks < 8; ++ks) {
                s16x8 a = *(const s16x8*)(w2row + ((ks * 32 + lg2 * 16) ^ swz));
                a2 = __builtin_amdgcn_mfma_f32_32x32x16_bf16(a, hb[ks], a2, 0, 0, 0);
            }
#pragma unroll
            for (int rh = 0; rh < 4; ++rh) {
                const f32x4 bv = *(const f32x4*)(b2s + nblk * 32 + rh * 8 + lg2 * 4);
                const int kb = nblk * 64 + rh * 16 + lg2 * 8;
                *(uint2*)(sw + l31 * 128 + (kb ^ swz)) =
                    pack_bf4(fmaxf(a2[rh * 4] + bv[0], 0.f), fmaxf(a2[rh * 4 + 1] + bv[1], 0.f),
                             fmaxf(a2[rh * 4 + 2] + bv[2], 0.f), fmaxf(a2[rh * 4 + 3] + bv[3], 0.f));
            }
        }
        asm volatile("s_waitcnt lgkmcnt(0)" ::: "memory");

        s16x8 wb[4];
#pragma unroll
        for (int ks = 0; ks < 4; ++ks)
            wb[ks] = *(const s16x8*)(sw + l31 * 128 + ((ks * 32 + lg2 * 16) ^ swz));

        s16x8 xbf;
        {
            f32x4 a0 = lg2 ? x2 : x0, a1 = lg2 ? x3 : x1;
#pragma unroll
            for (int i = 0; i < 4; ++i) {
                xbf[i] = (short)f2bf(a0[i]);
                xbf[i + 4] = (short)f2bf(a1[i]);
            }
        }
        f32x16 p = {0.f};
        p = __builtin_amdgcn_mfma_f32_32x32x16_bf16(b3f, xbf, p, 0, 0, 0);

#pragma unroll
        for (int nblk = 0; nblk < 16; ++nblk) {
            const char* __restrict__ arow = (const char*)w3t + ((nblk * 32 + l31) << 7);
            f32x16 d = {0.f};
#pragma unroll
            for (int ks = 0; ks < 4; ++ks) {
                s16x8 a = *(const s16x8*)(arow + ((ks * 32 + lg2 * 16) ^ swz));
                d = __builtin_amdgcn_mfma_f32_32x32x16_bf16(a, wb[ks], d, 0, 0, 0);
            }
            const float xs = (nblk < 4 ? x0 : nblk < 8 ? x1 : nblk < 12 ? x2 : x3)[nblk & 3];
#pragma unroll
            for (int r = 0; r < 16; ++r) p[r] = fmaf(xs, d[r], p[r]);
        }

        asm volatile("s_waitcnt lgkmcnt(0)" ::: "memory");
#pragma unroll
        for (int rh = 0; rh < 4; ++rh) {
            const int ob = rh * 16 + lg2 * 8;
            *(uint2*)(sw + l31 * 64 + (ob ^ ((l31 & 7) << 3))) =
                pack_bf4(p[rh * 4], p[rh * 4 + 1], p[rh * 4 + 2], p[rh * 4 + 3]);
        }
        asm volatile("s_waitcnt lgkmcnt(0)" ::: "memory");
#pragma unroll
        for (int q = 0; q < 2; ++q) {
            const int er = (lane >> 2) + q * 16;
            const int off = (lane & 3) * 16;
            const int s8 = (er & 7) << 3;
            uint2 a = *(const uint2*)(sw + er * 64 + (off ^ s8));
            uint2 b = *(const uint2*)(sw + er * 64 + ((off + 8) ^ s8));
            *(uint4*)((char*)msg + (size_t)chunk * 2048 + q * 1024 + lane * 16) =
                make_uint4(a.x, a.y, b.x, b.y);
        }
    }
}

// ---------------- fused: agg (LINEAR msg stream) + root + GAT1 node transform ----------------
__global__ __launch_bounds__(256) void k_aggt(
    const unsigned short* __restrict__ msg, const int* __restrict__ rowptr,
    const float* __restrict__ x,
    const float* __restrict__ rw, const float* __restrict__ cb,
    const float* __restrict__ W, const float* __restrict__ av_s, const float* __restrict__ av_d,
    unsigned* __restrict__ hbf, float* __restrict__ as_v, float* __restrict__ ad_v)
{
    const int n = (blockIdx.x * 256 + threadIdx.x) >> 6;
    if (n >= NN) return;
    const int lane = threadIdx.x & 63;
    const int half = lane >> 5, o = lane & 31;
    const int r0 = rowptr[n], r1 = rowptr[n + 1];
    float agg = 0.f;
    for (int j = r0 + half; j < r1; j += 2)
        agg += bf2f(msg[(size_t)j * 32 + o]);
    agg += __shfl_xor(agg, 32);
    const float* __restrict__ xr = x + (size_t)n * 16;
    float root = cb[o];
#pragma unroll
    for (int i = 0; i < 16; ++i) root = fmaf(xr[i], rw[i * 32 + o], root);
    const float h1v = fmaxf(agg + root, 0.f);
    float acc = 0.f;
#pragma unroll 8
    for (int i = 0; i < 32; ++i)
        acc = fmaf(__shfl(h1v, i), W[i * 64 + lane], acc);
    float s = acc * av_s[lane], d = acc * av_d[lane];
#pragma unroll
    for (int off = 32; off; off >>= 1) { s += __shfl_xor(s, off); d += __shfl_xor(d, off); }
    if (lane == 0) { as_v[n] = s; ad_v[n] = d; }
    const float nb = __shfl(acc, lane | 1);
    if (!(lane & 1)) hbf[(size_t)n * 32 + (lane >> 1)] = pack2(acc, nb);
}

// asp[j] = as_v[srcp[j]]
__global__ __launch_bounds__(256) void k_easrc(const int* __restrict__ srcp,
                                               const float* __restrict__ as_v,
                                               float* __restrict__ asp) {
    int j = blockIdx.x * 256 + threadIdx.x;
    if (j < NE) asp[j] = as_v[srcp[j]];
}

// ---------------- GAT1: softmax-gather + fused layer-2 node transform ----------------
__global__ __launch_bounds__(256) void k_gat1(
    const int* __restrict__ rowptr, const int* __restrict__ srcp, const float* __restrict__ asp,
    const unsigned* __restrict__ hbf, const float* __restrict__ as_v, const float* __restrict__ ad_v,
    const float* __restrict__ b,
    const float* __restrict__ W2, const float* __restrict__ av_s2, const float* __restrict__ av_d2,
    unsigned* __restrict__ hbf2, float* __restrict__ as_v2, float* __restrict__ ad_v2)
{
    const int n = (blockIdx.x * 256 + threadIdx.x) >> 6;
    if (n >= NN) return;
    const int lane = threadIdx.x & 63;
    const int fl = lane & 15, qw = lane >> 4;
    const int r0 = rowptr[n], r1 = rowptr[n + 1];
    const float adn = ad_v[n];
    const float l_self = lrelu(as_v[n] + adn);
    float m = l_self;
    for (int j = r0 + lane; j < r1; j += 64)
        m = fmaxf(m, lrelu(asp[j] + adn));
#pragma unroll
    for (int off = 32; off; off >>= 1) m = fmaxf(m, __shfl_xor(m, off));
    float s = 0.f;
    for (int j = r0 + lane; j < r1; j += 64)
        s += expf(lrelu(asp[j] + adn) - m);
#pragma unroll
    for (int off = 32; off; off >>= 1) s += __shfl_xor(s, off);
    const float w_self = expf(l_self - m);
    s += w_self;
    float a0 = 0.f, a1 = 0.f, a2 = 0.f, a3 = 0.f;
    if (qw == 0) {
        const uint2 hv = *(const uint2*)(hbf + (size_t)n * 32 + fl * 2);
        a0 = w_self * bf2f((unsigned short)(hv.x & 0xffff));
        a1 = w_self * bf2f((unsigned short)(hv.x >> 16));
        a2 = w_self * bf2f((unsigned short)(hv.y & 0xffff));
        a3 = w_self * bf2f((unsigned short)(hv.y >> 16));
    }
    for (int j = r0 + qw; j < r1; j += 4) {
        const int sn = srcp[j];
        const float w = expf(lrelu(asp[j] + adn) - m);
        const uint2 hv = *(const uint2*)(hbf + (size_t)sn * 32 + fl * 2);
        a0 = fmaf(w, bf2f((unsigned short)(hv.x & 0xffff)), a0);
        a1 = fmaf(w, bf2f((unsigned short)(hv.x >> 16)), a1);
        a2 = fmaf(w, bf2f((unsigned short)(hv.y & 0xffff)), a2);
        a3 = fmaf(w, bf2f((unsigned short)(hv.y >> 16)), a3);
    }
#pragma unroll
    for (int off = 16; off <= 32; off <<= 1) {
        a0 += __shfl_xor(a0, off);
        a1 += __shfl_xor(a1, off);
        a2 += __shfl_xor(a2, off);
        a3 += __shfl_xor(a3, off);
    }
    const float v0 = fmaxf(a0 / s + b[4 * fl], 0.f);
    const float v1 = fmaxf(a1 / s + b[4 * fl + 1], 0.f);
    const float v2 = fmaxf(a2 / s + b[4 * fl + 2], 0.f);
    const float v3 = fmaxf(a3 / s + b[4 * fl + 3], 0.f);
    float acc = 0.f;
#pragma unroll 8
    for (int i = 0; i < 64; ++i) {
        float hi;
        if ((i & 3) == 0) hi = __shfl(v0, i >> 2);
        else if ((i & 3) == 1) hi = __shfl(v1, i >> 2);
        else if ((i & 3) == 2) hi = __shfl(v2, i >> 2);
        else hi = __shfl(v3, i >> 2);
        acc = fmaf(hi, W2[i * 64 + lane], acc);
    }
    float s2 = acc * av_s2[lane], d2 = acc * av_d2[lane];
#pragma unroll
    for (int off = 32; off; off >>= 1) { s2 += __shfl_xor(s2, off); d2 += __shfl_xor(d2, off); }
    if (lane == 0) { as_v2[n] = s2; ad_v2[n] = d2; }
    const float nb = __shfl(acc, lane | 1);
    if (!(lane & 1)) hbf2[(size_t)n * 32 + (lane >> 1)] = pack2(acc, nb);
}

// ---------------- GAT2: softmax-gather, bf16 output ----------------
__global__ __launch_bounds__(256) void k_gat2(
    const int* __restrict__ rowptr, const int* __restrict__ srcp, const float* __restrict__ asp,
    const unsigned* __restrict__ hbf, const float* __restrict__ as_v, const float* __restrict__ ad_v,
    const float* __restrict__ b, unsigned* __restrict__ outbf)
{
    const int n = (blockIdx.x * 256 + threadIdx.x) >> 6;
    if (n >= NN) return;
    const int lane = threadIdx.x & 63;
    const int fl = lane & 15, qw = lane >> 4;
    const int r0 = rowptr[n], r1 = rowptr[n + 1];
    const float adn = ad_v[n];
    const float l_self = lrelu(as_v[n] + adn);
    float m = l_self;
    for (int j = r0 + lane; j < r1; j += 64)
        m = fmaxf(m, lrelu(asp[j] + adn));
#pragma unroll
    for (int off = 32; off; off >>= 1) m = fmaxf(m, __shfl_xor(m, off));
    float s = 0.f;
    for (int j = r0 + lane; j < r1; j += 64)
        s += expf(lrelu(asp[j] + adn) - m);
#pragma unroll
    for (int off = 32; off; off >>= 1) s += __shfl_xor(s, off);
    const float w_self = expf(l_self - m);
    s += w_self;
    float a0 = 0.f, a1 = 0.f, a2 = 0.f, a3 = 0.f;
    if (qw == 0) {
        const uint2 hv = *(const uint2*)(hbf + (size_t)n * 32 + fl * 2);
        a0 = w_self * bf2f((unsigned short)(hv.x & 0xffff));
        a1 = w_self * bf2f((unsigned short)(hv.x >> 16));
        a2 = w_self * bf2f((unsigned short)(hv.y & 0xffff));
        a3 = w_self * bf2f((unsigned short)(hv.y >> 16));
    }
    for (int j = r0 + qw; j < r1; j += 4) {
        const int sn = srcp[j];
        const float w = expf(lrelu(asp[j] + adn) - m);
        const uint2 hv = *(const uint2*)(hbf + (size_t)sn * 32 + fl * 2);
        a0 = fmaf(w, bf2f((unsigned short)(hv.x & 0xffff)), a0);
        a1 = fmaf(w, bf2f((unsigned short)(hv.x >> 16)), a1);
        a2 = fmaf(w, bf2f((unsigned short)(hv.y & 0xffff)), a2);
        a3 = fmaf(w, bf2f((unsigned short)(hv.y >> 16)), a3);
    }
#pragma unroll
    for (int off = 16; off <= 32; off <<= 1) {
        a0 += __shfl_xor(a0, off);
        a1 += __shfl_xor(a1, off);
        a2 += __shfl_xor(a2, off);
        a3 += __shfl_xor(a3, off);
    }
    if (qw == 0) {
        const float v0 = fmaxf(a0 / s + b[4 * fl], 0.f);
        const float v1 = fmaxf(a1 / s + b[4 * fl + 1], 0.f);
        const float v2 = fmaxf(a2 / s + b[4 * fl + 2], 0.f);
        const float v3 = fmaxf(a3 / s + b[4 * fl + 3], 0.f);
        *(uint2*)(outbf + (size_t)n * 32 + fl * 2) = make_uint2(pack2(v0, v1), pack2(v2, v3));
    }
}

// ---------------- global mean pool (bf16 input) ----------------
__global__ __launch_bounds__(256) void k_pool1(
    const unsigned* __restrict__ hbf, const int* __restrict__ batch,
    float* __restrict__ gsum, float* __restrict__ gcnt)
{
    __shared__ float ls[NG * 64];
    __shared__ float lc[NG];
    for (int j = threadIdx.x; j < NG * 64; j += 256) ls[j] = 0.f;
    if (threadIdx.x < NG) lc[threadIdx.x] = 0.f;
    __syncthreads();
    const int base = blockIdx.x * 512;
    for (int idx = threadIdx.x; idx < 512 * 32; idx += 256) {
        const int nl = idx >> 5, f2 = idx & 31;
        const int n = base + nl;
        if (n < NN) {
            const int g = batch[n];
            const unsigned hv = hbf[(size_t)n * 32 + f2];
            atomicAdd(&ls[g * 64 + 2 * f2], bf2f((unsigned short)(hv & 0xffff)));
            atomicAdd(&ls[g * 64 + 2 * f2 + 1], bf2f((unsigned short)(hv >> 16)));
            if (f2 == 0) atomicAdd(&lc[g], 1.f);
        }
    }
    __syncthreads();
    for (int j = threadIdx.x; j < NG * 64; j += 256) atomicAdd(&gsum[j], ls[j]);
    if (threadIdx.x < NG) atomicAdd(&gcnt[threadIdx.x], lc[threadIdx.x]);
}

__global__ __launch_bounds__(256) void k_pool2(
    const float* __restrict__ gsum, const float* __restrict__ gcnt, float* __restrict__ out)
{
    const int idx = blockIdx.x * 256 + threadIdx.x;
    if (idx >= NG * 64) return;
    out[idx] = gsum[idx] / fmaxf(gcnt[idx >> 6], 1.f);
}

extern "C" void kernel_launch(void* const* d_in, const int* in_sizes, int n_in,
                              void* d_out, int out_size, void* d_ws, size_t ws_size,
                              hipStream_t stream)
{
    const float* x     = (const float*)d_in[0];
    const float* ea    = (const float*)d_in[1];
    const int*   ei    = (const int*)d_in[2];
    const int*   batch = (const int*)d_in[3];
    const float* w1 = (const float*)d_in[4];   const float* b1 = (const float*)d_in[5];
    const float* w2 = (const float*)d_in[6];   const float* b2 = (const float*)d_in[7];
    const float* w3 = (const float*)d_in[8];   const float* b3 = (const float*)d_in[9];
    const float* rw = (const float*)d_in[10];  const float* cb = (const float*)d_in[11];
    const float* g1w  = (const float*)d_in[12]; const float* g1as = (const float*)d_in[13];
    const float* g1ad = (const float*)d_in[14]; const float* g1b  = (const float*)d_in[15];
    const float* g2w  = (const float*)d_in[16]; const float* g2as = (const float*)d_in[17];
    const float* g2ad = (const float*)d_in[18]; const float* g2b  = (const float*)d_in[19];
    const int* src = ei;
    const int* dst = ei + NE;
    float* out = (float*)d_out;
    (void)in_sizes; (void)n_in; (void)out_size; (void)ws_size;

    char* ws = (char*)d_ws;
    size_t off = 0;
    auto alloc = [&](size_t bytes) -> char* {
        char* p = ws + off;
        off += (bytes + 255) & ~(size_t)255;
        return p;
    };
    int*  deg    = (int*)alloc((size_t)NN * 4);
    int*  cursor = (int*)alloc((size_t)NN * 4);
    int*  rowptr = (int*)alloc((size_t)(NN + 1) * 4);
    int*  bsum   = (int*)alloc((size_t)NSB * 4);
    int*  eid    = (int*)alloc((size_t)NE * 4);
    int*  srcp   = (int*)alloc((size_t)NE * 4);
    float* asp   = (float*)alloc((size_t)NE * 4);
    unsigned short* w3t_g = (unsigned short*)alloc((size_t)64 * 512 * 2);
    unsigned short* w2t_g = (unsigned short*)alloc((size_t)64 * 128 * 2);
    unsigned short* w1p_g = (unsigned short*)alloc((size_t)128 * 16 * 2);
    unsigned short* b3t_g = (unsigned short*)alloc((size_t)512 * 2);
    unsigned short* msg   = (unsigned short*)alloc((size_t)NE * 32 * 2);  // 25.6 MB, CSR order
    unsigned* hT  = (unsigned*)alloc((size_t)NN * 32 * 4);
    unsigned* hT2 = (unsigned*)alloc((size_t)NN * 32 * 4);
    unsigned* hD  = (unsigned*)alloc((size_t)NN * 32 * 4);
    float* as_v  = (float*)alloc((size_t)NN * 4);
    float* ad_v  = (float*)alloc((size_t)NN * 4);
    float* as_v2 = (float*)alloc((size_t)NN * 4);
    float* ad_v2 = (float*)alloc((size_t)NN * 4);
    float* gsum = (float*)alloc((size_t)NG * 64 * 4);
    float* gcnt = (float*)alloc((size_t)NG * 4);

    hipMemsetAsync(deg, 0, (size_t)NN * 4, stream);
    hipMemsetAsync(gsum, 0, (size_t)NG * 64 * 4, stream);
    hipMemsetAsync(gcnt, 0, (size_t)NG * 4, stream);

    // CSR build
    k_hist<<<(NE + 255) / 256, 256, 0, stream>>>(dst, deg);
    k_bsum<<<NSB, 256, 0, stream>>>(deg, bsum);
    k_scan2<<<NSB, 256, 0, stream>>>(deg, bsum, rowptr, cursor);
    k_perm<<<(NE + 255) / 256, 256, 0, stream>>>(dst, src, cursor, eid, srcp);

    // NNConv (fused, all-MFMA, CSR-ordered output)
    k_wprep<<<(64 * 512 + 255) / 256, 256, 0, stream>>>(w3, w2, w1, b1, b3,
                                                        w3t_g, w2t_g, w1p_g, b3t_g);
    k_fused<<<FUSED_GRID, 512, 0, stream>>>(ea, eid, w1p_g, w2t_g, b2, w3t_g, b3t_g, srcp, x, msg);

    // agg (linear msg) + root + GAT1 transform (fused)
    k_aggt<<<(NN * 64 + 255) / 256, 256, 0, stream>>>(msg, rowptr, x, rw, cb,
                                                      g1w, g1as, g1ad, hT, as_v, ad_v);
    // GAT layer 1 (+ fused layer-2 transform)
    k_easrc<<<(NE + 255) / 256, 256, 0, stream>>>(srcp, as_v, asp);
    k_gat1<<<(NN * 64 + 255) / 256, 256, 0, stream>>>(rowptr, srcp, asp, hT, as_v, ad_v, g1b,
                                                      g2w, g2as, g2ad, hT2, as_v2, ad_v2);
    // GAT layer 2
    k_easrc<<<(NE + 255) / 256, 256, 0, stream>>>(srcp, as_v2, asp);
    k_gat2<<<(NN * 64 + 255) / 256, 256, 0, stream>>>(rowptr, srcp, asp, hT2, as_v2, ad_v2, g2b, hD);

    // pool
    k_pool1<<<(NN + 511) / 512, 256, 0, stream>>>(hD, batch, gsum, gcnt);
    k_pool2<<<(NG * 64 + 255) / 256, 256, 0, stream>>>(gsum, gcnt, out);
}

// Round 15
// 306.047 us; speedup vs baseline: 1.3684x; 1.0166x over previous
//
#include <hip/hip_runtime.h>

#define NN 50000
#define NE 400000
#define NG 32
#define SLOPE 0.2f
#define NSB ((NN + 255) / 256)   // 196 scan blocks

typedef __attribute__((ext_vector_type(4))) float f32x4;
typedef __attribute__((ext_vector_type(16))) float f32x16;
typedef __attribute__((ext_vector_type(8))) short s16x8;

__device__ __forceinline__ float lrelu(float v) { return v > 0.f ? v : SLOPE * v; }
__device__ __forceinline__ unsigned short f2bf(float f) {
    union { float f; unsigned u; } c; c.f = f;
    unsigned r = c.u + 0x7fffu + ((c.u >> 16) & 1u);
    return (unsigned short)(r >> 16);
}
__device__ __forceinline__ float bf2f(unsigned short b) {
    union { unsigned u; float f; } c; c.u = ((unsigned)b) << 16; return c.f;
}
__device__ __forceinline__ unsigned pack2(float a, float b) {
    return (unsigned)f2bf(a) | ((unsigned)f2bf(b) << 16);
}
__device__ __forceinline__ uint2 pack_bf4(float a, float b, float c, float d) {
    uint2 u;
    u.x = pack2(a, b);
    u.y = pack2(c, d);
    return u;
}

// ---------------- CSR build ----------------
__global__ __launch_bounds__(256) void k_hist(const int* __restrict__ dst, int* __restrict__ deg) {
    int e = blockIdx.x * 256 + threadIdx.x;
    if (e < NE) atomicAdd(&deg[dst[e]], 1);
}

__global__ __launch_bounds__(256) void k_bsum(const int* __restrict__ deg, int* __restrict__ bsum) {
    __shared__ int ls[256];
    const int t = threadIdx.x;
    const int idx = blockIdx.x * 256 + t;
    ls[t] = (idx < NN) ? deg[idx] : 0;
    __syncthreads();
#pragma unroll
    for (int off = 128; off; off >>= 1) {
        if (t < off) ls[t] += ls[t + off];
        __syncthreads();
    }
    if (t == 0) bsum[blockIdx.x] = ls[0];
}

__global__ __launch_bounds__(256) void k_scan2(const int* __restrict__ deg,
                                               const int* __restrict__ bsum,
                                               int* __restrict__ rowptr, int* __restrict__ cursor) {
    __shared__ int lb[256];
    __shared__ int ls[256];
    const int t = threadIdx.x, b = blockIdx.x;
    lb[t] = (t < NSB && t < b) ? bsum[t] : 0;
    const int idx = b * 256 + t;
    const int v = (idx < NN) ? deg[idx] : 0;
    ls[t] = v;
    __syncthreads();
#pragma unroll
    for (int off = 128; off; off >>= 1) {
        if (t < off) lb[t] += lb[t + off];
        __syncthreads();
    }
#pragma unroll
    for (int off = 1; off < 256; off <<= 1) {
        int u = (t >= off) ? ls[t - off] : 0;
        __syncthreads();
        ls[t] += u;
        __syncthreads();
    }
    if (idx < NN) {
        const int run = lb[0] + ls[t] - v;
        rowptr[idx] = run;
        cursor[idx] = run;
    }
    if (b == 0 && t == 0) rowptr[NN] = NE;
}

// emits srcp (src in CSR order) and eap (edge attrs in CSR order, float4-padded)
__global__ __launch_bounds__(256) void k_perm(const int* __restrict__ dst, const int* __restrict__ src,
                                              const float* __restrict__ ea,
                                              int* __restrict__ cursor,
                                              int* __restrict__ srcp, float* __restrict__ eap) {
    int e = blockIdx.x * 256 + threadIdx.x;
    if (e < NE) {
        int p = atomicAdd(&cursor[dst[e]], 1);
        srcp[p] = src[e];
        *(float4*)(eap + (size_t)p * 4) =
            make_float4(ea[e * 3], ea[e * 3 + 1], ea[e * 3 + 2], 0.f);
    }
}

// ---------------- one-time weight prep ----------------
__global__ __launch_bounds__(256) void k_wprep(const float* __restrict__ w3,
                                               const float* __restrict__ w2,
                                               const float* __restrict__ w1,
                                               const float* __restrict__ b1,
                                               const float* __restrict__ b3,
                                               unsigned short* __restrict__ w3t_g,
                                               unsigned short* __restrict__ w2t_g,
                                               unsigned short* __restrict__ w1p_g,
                                               unsigned short* __restrict__ b3t_g) {
    const int v = blockIdx.x * 256 + threadIdx.x;
    if (v < 64 * 512) {
        const int k = v >> 9, n = v & 511;
        const int byte = (n << 7) | ((k << 1) ^ ((n & 7) << 4));
        *(unsigned short*)((char*)w3t_g + byte) = f2bf(w3[v]);
    }
    if (v < 64 * 128) {
        const int o = v & 63, slot = v >> 6;
        const int ks = slot >> 4, lg2 = (slot >> 3) & 1, j = slot & 7;
        const int kp = (ks >> 1) * 32 + (j & 3) + 8 * (j >> 2) + 16 * (ks & 1) + 4 * lg2;
        const int byte = (o << 8) | ((slot << 1) ^ ((o & 7) << 4));
        *(unsigned short*)((char*)w2t_g + byte) = f2bf(w2[kp * 64 + o]);
    }
    if (v < 128 * 16) {
        const int j = v >> 4, k = v & 15;
        float val = (k < 3) ? w1[k * 128 + j] : (k == 3 ? b1[j] : 0.f);
        w1p_g[v] = f2bf(val);
    }
    if (v < 512) {
        const int i = v >> 5, o = v & 31;
        b3t_g[o * 16 + i] = f2bf(b3[v]);
    }
}

// ---------------- fused NNConv, all-MFMA, 32 edges/chunk, fully linear except x[srcp] ------
#define FUSED_GRID 256
#define NCHUNK (NE / 32)
__global__ __launch_bounds__(512, 1) void k_fused(
    const float* __restrict__ eap,
    const unsigned short* __restrict__ w1p_g,
    const unsigned short* __restrict__ w2t_g, const float* __restrict__ b2,
    const unsigned short* __restrict__ w3t_g, const unsigned short* __restrict__ b3t_g,
    const int* __restrict__ srcp, const float* __restrict__ x,
    unsigned short* __restrict__ msg)
{
    __shared__ __align__(16) unsigned short w3t[512 * 64];
    __shared__ __align__(16) unsigned short w2t[64 * 128];
    __shared__ __align__(16) unsigned short w1p[128 * 16];
    __shared__ __align__(16) unsigned short b3t[512];
    __shared__ __align__(16) float b2s[64];
    __shared__ __align__(16) unsigned slab[8][1024];

    const int t = threadIdx.x;
    {
        const uint4* g = (const uint4*)w3t_g;
        uint4* l = (uint4*)w3t;
        for (int v = t; v < 4096; v += 512) l[v] = g[v];
        const uint4* g2 = (const uint4*)w2t_g;
        uint4* l2 = (uint4*)w2t;
        for (int v = t; v < 1024; v += 512) l2[v] = g2[v];
    }
    if (t < 256) ((uint4*)w1p)[t] = ((const uint4*)w1p_g)[t];
    if (t < 64)  ((uint4*)b3t)[t] = ((const uint4*)b3t_g)[t];
    if (t < 64)  b2s[t] = b2[t];
    __syncthreads();

    const int wid = t >> 6, lane = t & 63;
    const int l31 = lane & 31, lg2 = lane >> 5;
    char* sw = (char*)slab[wid];
    const int swz = (l31 & 7) << 4;

    s16x8 w1pf[4];
#pragma unroll
    for (int n = 0; n < 4; ++n)
        w1pf[n] = *(const s16x8*)((const char*)w1p + ((n * 32 + l31) << 5) + lg2 * 16);
    s16x8 b3f = *(const s16x8*)((const char*)b3t + (l31 << 5) + lg2 * 16);

    for (int chunk = blockIdx.x * 8 + wid; chunk < NCHUNK; chunk += FUSED_GRID * 8) {
        const int jpos = chunk * 32 + l31;
        const int sn = srcp[jpos];
        const f32x4* __restrict__ xp = (const f32x4*)(x + (size_t)sn * 16);
        f32x4 x0 = xp[0], x1 = xp[1], x2 = xp[2], x3 = xp[3];
        const f32x4 eav = *(const f32x4*)(eap + (size_t)jpos * 4);

        // ---- L1: 4 MFMAs, pack D into L2 B-fragments ----
        s16x8 eb = (s16x8){0, 0, 0, 0, 0, 0, 0, 0};
        if (lg2 == 0) {
            eb[0] = (short)f2bf(eav[0]); eb[1] = (short)f2bf(eav[1]);
            eb[2] = (short)f2bf(eav[2]); eb[3] = (short)0x3F80;  // 1.0
        }
        s16x8 hb[8];
#pragma unroll
        for (int n = 0; n < 4; ++n) {
            f32x16 d = {0.f};
            d = __builtin_amdgcn_mfma_f32_32x32x16_bf16(w1pf[n], eb, d, 0, 0, 0);
#pragma unroll
            for (int s = 0; s < 2; ++s)
#pragma unroll
                for (int j = 0; j < 8; ++j)
                    hb[2 * n + s][j] = (short)f2bf(fmaxf(d[(j & 3) + 4 * (j >> 2) + 8 * s], 0.f));
        }

        // ---- L2: h2 = relu(w2t @ h1 + b2), 16 MFMAs; b2 added at pack from LDS ----
        asm volatile("s_waitcnt lgkmcnt(0)" ::: "memory");
#pragma unroll
        for (int nblk = 0; nblk < 2; ++nblk) {
            f32x16 a2 = {0.f};
            const char* __restrict__ w2row = (const char*)w2t + ((nblk * 32 + l31) << 8);
#pragma unroll
            for (int ks = 0; ks < 8; ++ks) {
                s16x8 a = *(const s16x8*)(w2row + ((ks * 32 + lg2 * 16) ^ swz));
                a2 = __builtin_amdgcn_mfma_f32_32x32x16_bf16(a, hb[ks], a2, 0, 0, 0);
            }
#pragma unroll
            for (int rh = 0; rh < 4; ++rh) {
                const f32x4 bv = *(const f32x4*)(b2s + nblk * 32 + rh * 8 + lg2 * 4);
                const int kb = nblk * 64 + rh * 16 + lg2 * 8;
                *(uint2*)(sw + l31 * 128 + (kb ^ swz)) =
                    pack_bf4(fmaxf(a2[rh * 4] + bv[0], 0.f), fmaxf(a2[rh * 4 + 1] + bv[1], 0.f),
                             fmaxf(a2[rh * 4 + 2] + bv[2], 0.f), fmaxf(a2[rh * 4 + 3] + bv[3], 0.f));
            }
        }
        asm volatile("s_waitcnt lgkmcnt(0)" ::: "memory");

        s16x8 wb[4];
#pragma unroll
        for (int ks = 0; ks < 4; ++ks)
            wb[ks] = *(const s16x8*)(sw + l31 * 128 + ((ks * 32 + lg2 * 16) ^ swz));

        s16x8 xbf;
        {
            f32x4 a0 = lg2 ? x2 : x0, a1 = lg2 ? x3 : x1;
#pragma unroll
            for (int i = 0; i < 4; ++i) {
                xbf[i] = (short)f2bf(a0[i]);
                xbf[i + 4] = (short)f2bf(a1[i]);
            }
        }
        f32x16 p = {0.f};
        p = __builtin_amdgcn_mfma_f32_32x32x16_bf16(b3f, xbf, p, 0, 0, 0);

#pragma unroll
        for (int nblk = 0; nblk < 16; ++nblk) {
            const char* __restrict__ arow = (const char*)w3t + ((nblk * 32 + l31) << 7);
            f32x16 d = {0.f};
#pragma unroll
            for (int ks = 0; ks < 4; ++ks) {
                s16x8 a = *(const s16x8*)(arow + ((ks * 32 + lg2 * 16) ^ swz));
                d = __builtin_amdgcn_mfma_f32_32x32x16_bf16(a, wb[ks], d, 0, 0, 0);
            }
            const float xs = (nblk < 4 ? x0 : nblk < 8 ? x1 : nblk < 12 ? x2 : x3)[nblk & 3];
#pragma unroll
            for (int r = 0; r < 16; ++r) p[r] = fmaf(xs, d[r], p[r]);
        }

        asm volatile("s_waitcnt lgkmcnt(0)" ::: "memory");
#pragma unroll
        for (int rh = 0; rh < 4; ++rh) {
            const int ob = rh * 16 + lg2 * 8;
            *(uint2*)(sw + l31 * 64 + (ob ^ ((l31 & 7) << 3))) =
                pack_bf4(p[rh * 4], p[rh * 4 + 1], p[rh * 4 + 2], p[rh * 4 + 3]);
        }
        asm volatile("s_waitcnt lgkmcnt(0)" ::: "memory");
#pragma unroll
        for (int q = 0; q < 2; ++q) {
            const int er = (lane >> 2) + q * 16;
            const int off = (lane & 3) * 16;
            const int s8 = (er & 7) << 3;
            uint2 a = *(const uint2*)(sw + er * 64 + (off ^ s8));
            uint2 b = *(const uint2*)(sw + er * 64 + ((off + 8) ^ s8));
            *(uint4*)((char*)msg + (size_t)chunk * 2048 + q * 1024 + lane * 16) =
                make_uint4(a.x, a.y, b.x, b.y);
        }
    }
}

// ---------------- fused: agg (LINEAR msg stream) + root + GAT1 node transform ----------------
__global__ __launch_bounds__(256) void k_aggt(
    const unsigned short* __restrict__ msg, const int* __restrict__ rowptr,
    const float* __restrict__ x,
    const float* __restrict__ rw, const float* __restrict__ cb,
    const float* __restrict__ W, const float* __restrict__ av_s, const float* __restrict__ av_d,
    unsigned* __restrict__ hbf, float* __restrict__ as_v, float* __restrict__ ad_v)
{
    const int n = (blockIdx.x * 256 + threadIdx.x) >> 6;
    if (n >= NN) return;
    const int lane = threadIdx.x & 63;
    const int half = lane >> 5, o = lane & 31;
    const int r0 = rowptr[n], r1 = rowptr[n + 1];
    float agg = 0.f;
    for (int j = r0 + half; j < r1; j += 2)
        agg += bf2f(msg[(size_t)j * 32 + o]);
    agg += __shfl_xor(agg, 32);
    const float* __restrict__ xr = x + (size_t)n * 16;
    float root = cb[o];
#pragma unroll
    for (int i = 0; i < 16; ++i) root = fmaf(xr[i], rw[i * 32 + o], root);
    const float h1v = fmaxf(agg + root, 0.f);
    float acc = 0.f;
#pragma unroll 8
    for (int i = 0; i < 32; ++i)
        acc = fmaf(__shfl(h1v, i), W[i * 64 + lane], acc);
    float s = acc * av_s[lane], d = acc * av_d[lane];
#pragma unroll
    for (int off = 32; off; off >>= 1) { s += __shfl_xor(s, off); d += __shfl_xor(d, off); }
    if (lane == 0) { as_v[n] = s; ad_v[n] = d; }
    const float nb = __shfl(acc, lane | 1);
    if (!(lane & 1)) hbf[(size_t)n * 32 + (lane >> 1)] = pack2(acc, nb);
}

// asp[j] = as_v[srcp[j]]
__global__ __launch_bounds__(256) void k_easrc(const int* __restrict__ srcp,
                                               const float* __restrict__ as_v,
                                               float* __restrict__ asp) {
    int j = blockIdx.x * 256 + threadIdx.x;
    if (j < NE) asp[j] = as_v[srcp[j]];
}

// ---------------- GAT1: softmax-gather + fused layer-2 node transform ----------------
__global__ __launch_bounds__(256) void k_gat1(
    const int* __restrict__ rowptr, const int* __restrict__ srcp, const float* __restrict__ asp,
    const unsigned* __restrict__ hbf, const float* __restrict__ as_v, const float* __restrict__ ad_v,
    const float* __restrict__ b,
    const float* __restrict__ W2, const float* __restrict__ av_s2, const float* __restrict__ av_d2,
    unsigned* __restrict__ hbf2, float* __restrict__ as_v2, float* __restrict__ ad_v2)
{
    const int n = (blockIdx.x * 256 + threadIdx.x) >> 6;
    if (n >= NN) return;
    const int lane = threadIdx.x & 63;
    const int fl = lane & 15, qw = lane >> 4;
    const int r0 = rowptr[n], r1 = rowptr[n + 1];
    const float adn = ad_v[n];
    const float l_self = lrelu(as_v[n] + adn);
    float m = l_self;
    for (int j = r0 + lane; j < r1; j += 64)
        m = fmaxf(m, lrelu(asp[j] + adn));
#pragma unroll
    for (int off = 32; off; off >>= 1) m = fmaxf(m, __shfl_xor(m, off));
    float s = 0.f;
    for (int j = r0 + lane; j < r1; j += 64)
        s += expf(lrelu(asp[j] + adn) - m);
#pragma unroll
    for (int off = 32; off; off >>= 1) s += __shfl_xor(s, off);
    const float w_self = expf(l_self - m);
    s += w_self;
    float a0 = 0.f, a1 = 0.f, a2 = 0.f, a3 = 0.f;
    if (qw == 0) {
        const uint2 hv = *(const uint2*)(hbf + (size_t)n * 32 + fl * 2);
        a0 = w_self * bf2f((unsigned short)(hv.x & 0xffff));
        a1 = w_self * bf2f((unsigned short)(hv.x >> 16));
        a2 = w_self * bf2f((unsigned short)(hv.y & 0xffff));
        a3 = w_self * bf2f((unsigned short)(hv.y >> 16));
    }
    for (int j = r0 + qw; j < r1; j += 4) {
        const int sn = srcp[j];
        const float w = expf(lrelu(asp[j] + adn) - m);
        const uint2 hv = *(const uint2*)(hbf + (size_t)sn * 32 + fl * 2);
        a0 = fmaf(w, bf2f((unsigned short)(hv.x & 0xffff)), a0);
        a1 = fmaf(w, bf2f((unsigned short)(hv.x >> 16)), a1);
        a2 = fmaf(w, bf2f((unsigned short)(hv.y & 0xffff)), a2);
        a3 = fmaf(w, bf2f((unsigned short)(hv.y >> 16)), a3);
    }
#pragma unroll
    for (int off = 16; off <= 32; off <<= 1) {
        a0 += __shfl_xor(a0, off);
        a1 += __shfl_xor(a1, off);
        a2 += __shfl_xor(a2, off);
        a3 += __shfl_xor(a3, off);
    }
    const float v0 = fmaxf(a0 / s + b[4 * fl], 0.f);
    const float v1 = fmaxf(a1 / s + b[4 * fl + 1], 0.f);
    const float v2 = fmaxf(a2 / s + b[4 * fl + 2], 0.f);
    const float v3 = fmaxf(a3 / s + b[4 * fl + 3], 0.f);
    float acc = 0.f;
#pragma unroll 8
    for (int i = 0; i < 64; ++i) {
        float hi;
        if ((i & 3) == 0) hi = __shfl(v0, i >> 2);
        else if ((i & 3) == 1) hi = __shfl(v1, i >> 2);
        else if ((i & 3) == 2) hi = __shfl(v2, i >> 2);
        else hi = __shfl(v3, i >> 2);
        acc = fmaf(hi, W2[i * 64 + lane], acc);
    }
    float s2 = acc * av_s2[lane], d2 = acc * av_d2[lane];
#pragma unroll
    for (int off = 32; off; off >>= 1) { s2 += __shfl_xor(s2, off); d2 += __shfl_xor(d2, off); }
    if (lane == 0) { as_v2[n] = s2; ad_v2[n] = d2; }
    const float nb = __shfl(acc, lane | 1);
    if (!(lane & 1)) hbf2[(size_t)n * 32 + (lane >> 1)] = pack2(acc, nb);
}

// ---------------- GAT2: softmax-gather, bf16 output ----------------
__global__ __launch_bounds__(256) void k_gat2(
    const int* __restrict__ rowptr, const int* __restrict__ srcp, const float* __restrict__ asp,
    const unsigned* __restrict__ hbf, const float* __restrict__ as_v, const float* __restrict__ ad_v,
    const float* __restrict__ b, unsigned* __restrict__ outbf)
{
    const int n = (blockIdx.x * 256 + threadIdx.x) >> 6;
    if (n >= NN) return;
    const int lane = threadIdx.x & 63;
    const int fl = lane & 15, qw = lane >> 4;
    const int r0 = rowptr[n], r1 = rowptr[n + 1];
    const float adn = ad_v[n];
    const float l_self = lrelu(as_v[n] + adn);
    float m = l_self;
    for (int j = r0 + lane; j < r1; j += 64)
        m = fmaxf(m, lrelu(asp[j] + adn));
#pragma unroll
    for (int off = 32; off; off >>= 1) m = fmaxf(m, __shfl_xor(m, off));
    float s = 0.f;
    for (int j = r0 + lane; j < r1; j += 64)
        s += expf(lrelu(asp[j] + adn) - m);
#pragma unroll
    for (int off = 32; off; off >>= 1) s += __shfl_xor(s, off);
    const float w_self = expf(l_self - m);
    s += w_self;
    float a0 = 0.f, a1 = 0.f, a2 = 0.f, a3 = 0.f;
    if (qw == 0) {
        const uint2 hv = *(const uint2*)(hbf + (size_t)n * 32 + fl * 2);
        a0 = w_self * bf2f((unsigned short)(hv.x & 0xffff));
        a1 = w_self * bf2f((unsigned short)(hv.x >> 16));
        a2 = w_self * bf2f((unsigned short)(hv.y & 0xffff));
        a3 = w_self * bf2f((unsigned short)(hv.y >> 16));
    }
    for (int j = r0 + qw; j < r1; j += 4) {
        const int sn = srcp[j];
        const float w = expf(lrelu(asp[j] + adn) - m);
        const uint2 hv = *(const uint2*)(hbf + (size_t)sn * 32 + fl * 2);
        a0 = fmaf(w, bf2f((unsigned short)(hv.x & 0xffff)), a0);
        a1 = fmaf(w, bf2f((unsigned short)(hv.x >> 16)), a1);
        a2 = fmaf(w, bf2f((unsigned short)(hv.y & 0xffff)), a2);
        a3 = fmaf(w, bf2f((unsigned short)(hv.y >> 16)), a3);
    }
#pragma unroll
    for (int off = 16; off <= 32; off <<= 1) {
        a0 += __shfl_xor(a0, off);
        a1 += __shfl_xor(a1, off);
        a2 += __shfl_xor(a2, off);
        a3 += __shfl_xor(a3, off);
    }
    if (qw == 0) {
        const float v0 = fmaxf(a0 / s + b[4 * fl], 0.f);
        const float v1 = fmaxf(a1 / s + b[4 * fl + 1], 0.f);
        const float v2 = fmaxf(a2 / s + b[4 * fl + 2], 0.f);
        const float v3 = fmaxf(a3 / s + b[4 * fl + 3], 0.f);
        *(uint2*)(outbf + (size_t)n * 32 + fl * 2) = make_uint2(pack2(v0, v1), pack2(v2, v3));
    }
}

// ---------------- global mean pool (bf16 input) ----------------
__global__ __launch_bounds__(256) void k_pool1(
    const unsigned* __restrict__ hbf, const int* __restrict__ batch,
    float* __restrict__ gsum, float* __restrict__ gcnt)
{
    __shared__ float ls[NG * 64];
    __shared__ float lc[NG];
    for (int j = threadIdx.x; j < NG * 64; j += 256) ls[j] = 0.f;
    if (threadIdx.x < NG) lc[threadIdx.x] = 0.f;
    __syncthreads();
    const int base = blockIdx.x * 512;
    for (int idx = threadIdx.x; idx < 512 * 32; idx += 256) {
        const int nl = idx >> 5, f2 = idx & 31;
        const int n = base + nl;
        if (n < NN) {
            const int g = batch[n];
            const unsigned hv = hbf[(size_t)n * 32 + f2];
            atomicAdd(&ls[g * 64 + 2 * f2], bf2f((unsigned short)(hv & 0xffff)));
            atomicAdd(&ls[g * 64 + 2 * f2 + 1], bf2f((unsigned short)(hv >> 16)));
            if (f2 == 0) atomicAdd(&lc[g], 1.f);
        }
    }
    __syncthreads();
    for (int j = threadIdx.x; j < NG * 64; j += 256) atomicAdd(&gsum[j], ls[j]);
    if (threadIdx.x < NG) atomicAdd(&gcnt[threadIdx.x], lc[threadIdx.x]);
}

__global__ __launch_bounds__(256) void k_pool2(
    const float* __restrict__ gsum, const float* __restrict__ gcnt, float* __restrict__ out)
{
    const int idx = blockIdx.x * 256 + threadIdx.x;
    if (idx >= NG * 64) return;
    out[idx] = gsum[idx] / fmaxf(gcnt[idx >> 6], 1.f);
}

extern "C" void kernel_launch(void* const* d_in, const int* in_sizes, int n_in,
                              void* d_out, int out_size, void* d_ws, size_t ws_size,
                              hipStream_t stream)
{
    const float* x     = (const float*)d_in[0];
    const float* ea    = (const float*)d_in[1];
    const int*   ei    = (const int*)d_in[2];
    const int*   batch = (const int*)d_in[3];
    const float* w1 = (const float*)d_in[4];   const float* b1 = (const float*)d_in[5];
    const float* w2 = (const float*)d_in[6];   const float* b2 = (const float*)d_in[7];
    const float* w3 = (const float*)d_in[8];   const float* b3 = (const float*)d_in[9];
    const float* rw = (const float*)d_in[10];  const float* cb = (const float*)d_in[11];
    const float* g1w  = (const float*)d_in[12]; const float* g1as = (const float*)d_in[13];
    const float* g1ad = (const float*)d_in[14]; const float* g1b  = (const float*)d_in[15];
    const float* g2w  = (const float*)d_in[16]; const float* g2as = (const float*)d_in[17];
    const float* g2ad = (const float*)d_in[18]; const float* g2b  = (const float*)d_in[19];
    const int* src = ei;
    const int* dst = ei + NE;
    float* out = (float*)d_out;
    (void)in_sizes; (void)n_in; (void)out_size; (void)ws_size;

    char* ws = (char*)d_ws;
    size_t off = 0;
    auto alloc = [&](size_t bytes) -> char* {
        char* p = ws + off;
        off += (bytes + 255) & ~(size_t)255;
        return p;
    };
    int*  deg    = (int*)alloc((size_t)NN * 4);
    int*  cursor = (int*)alloc((size_t)NN * 4);
    int*  rowptr = (int*)alloc((size_t)(NN + 1) * 4);
    int*  bsum   = (int*)alloc((size_t)NSB * 4);
    int*  srcp   = (int*)alloc((size_t)NE * 4);
    float* eap   = (float*)alloc((size_t)NE * 4 * 4);   // CSR-ordered edge attrs, float4
    float* asp   = (float*)alloc((size_t)NE * 4);
    unsigned short* w3t_g = (unsigned short*)alloc((size_t)64 * 512 * 2);
    unsigned short* w2t_g = (unsigned short*)alloc((size_t)64 * 128 * 2);
    unsigned short* w1p_g = (unsigned short*)alloc((size_t)128 * 16 * 2);
    unsigned short* b3t_g = (unsigned short*)alloc((size_t)512 * 2);
    unsigned short* msg   = (unsigned short*)alloc((size_t)NE * 32 * 2);  // 25.6 MB, CSR order
    unsigned* hT  = (unsigned*)alloc((size_t)NN * 32 * 4);
    unsigned* hT2 = (unsigned*)alloc((size_t)NN * 32 * 4);
    unsigned* hD  = (unsigned*)alloc((size_t)NN * 32 * 4);
    float* as_v  = (float*)alloc((size_t)NN * 4);
    float* ad_v  = (float*)alloc((size_t)NN * 4);
    float* as_v2 = (float*)alloc((size_t)NN * 4);
    float* ad_v2 = (float*)alloc((size_t)NN * 4);
    float* gsum = (float*)alloc((size_t)NG * 64 * 4);
    float* gcnt = (float*)alloc((size_t)NG * 4);

    hipMemsetAsync(deg, 0, (size_t)NN * 4, stream);
    hipMemsetAsync(gsum, 0, (size_t)NG * 64 * 4, stream);
    hipMemsetAsync(gcnt, 0, (size_t)NG * 4, stream);

    // CSR build (+ CSR-ordered src and edge attrs)
    k_hist<<<(NE + 255) / 256, 256, 0, stream>>>(dst, deg);
    k_bsum<<<NSB, 256, 0, stream>>>(deg, bsum);
    k_scan2<<<NSB, 256, 0, stream>>>(deg, bsum, rowptr, cursor);
    k_perm<<<(NE + 255) / 256, 256, 0, stream>>>(dst, src, ea, cursor, srcp, eap);

    // NNConv (fused, all-MFMA, fully-linear inputs except x[srcp])
    k_wprep<<<(64 * 512 + 255) / 256, 256, 0, stream>>>(w3, w2, w1, b1, b3,
                                                        w3t_g, w2t_g, w1p_g, b3t_g);
    k_fused<<<FUSED_GRID, 512, 0, stream>>>(eap, w1p_g, w2t_g, b2, w3t_g, b3t_g, srcp, x, msg);

    // agg (linear msg) + root + GAT1 transform (fused)
    k_aggt<<<(NN * 64 + 255) / 256, 256, 0, stream>>>(msg, rowptr, x, rw, cb,
                                                      g1w, g1as, g1ad, hT, as_v, ad_v);
    // GAT layer 1 (+ fused layer-2 transform)
    k_easrc<<<(NE + 255) / 256, 256, 0, stream>>>(srcp, as_v, asp);
    k_gat1<<<(NN * 64 + 255) / 256, 256, 0, stream>>>(rowptr, srcp, asp, hT, as_v, ad_v, g1b,
                                                      g2w, g2as, g2ad, hT2, as_v2, ad_v2);
    // GAT layer 2
    k_easrc<<<(NE + 255) / 256, 256, 0, stream>>>(srcp, as_v2, asp);
    k_gat2<<<(NN * 64 + 255) / 256, 256, 0, stream>>>(rowptr, srcp, asp, hT2, as_v2, ad_v2, g2b, hD);

    // pool
    k_pool1<<<(NN + 511) / 512, 256, 0, stream>>>(hD, batch, gsum, gcnt);
    k_pool2<<<(NG * 64 + 255) / 256, 256, 0, stream>>>(gsum, gcnt, out);
}